// Round 1
// baseline (667.944 us; speedup 1.0000x reference)
//
#include <hip/hip_runtime.h>
#include <math.h>

#define B_S   2
#define PIX   4096
#define LL    20480
#define NS    16
#define RR    8
#define NCHK  128     // chunks per sequence
#define LC    160     // steps per chunk
#define SUBS  40      // steps per LDS staging sub-chunk
#define NSUB  4       // LC/SUBS

// ---------------- affine grid + bilinear grid_sample ----------------
__global__ __launch_bounds__(256)
void k_warp(const float* __restrict__ x, const float* __restrict__ nam,
            float* __restrict__ warped) {
  int g = blockIdx.x * 256 + threadIdx.x;        // B*K*C*PIX = 5,242,880
  int p  = g & 4095;
  int c  = (g >> 12) & 127;
  int bk = g >> 19;                              // 0..9
  int b = bk / 5, k = bk - b * 5;
  const float* th = nam + (size_t)(b * 25 + k) * 6;   // nam[b,0,k]
  float gx = ((p & 63) + 0.5f) * 0.03125f - 1.0f;
  float gy = ((p >> 6) + 0.5f) * 0.03125f - 1.0f;
  float grx = th[0] * gx + th[1] * gy + th[2];
  float gry = th[3] * gx + th[4] * gy + th[5];
  float ix = ((grx + 1.0f) * 64.0f - 1.0f) * 0.5f;
  float iy = ((gry + 1.0f) * 64.0f - 1.0f) * 0.5f;
  float x0 = floorf(ix), y0 = floorf(iy);
  float fx = ix - x0,  fy = iy - y0;
  const float* src = x + (size_t)(bk * 128 + c) * PIX;
  float acc = 0.0f;
  #pragma unroll
  for (int dy = 0; dy < 2; ++dy) {
    float yf = y0 + dy;
    float wy = dy ? fy : 1.0f - fy;
    if (yf < 0.0f || yf > 63.0f) continue;
    int yi = (int)yf;
    #pragma unroll
    for (int dx = 0; dx < 2; ++dx) {
      float xf = x0 + dx;
      float wx = dx ? fx : 1.0f - fx;
      if (xf < 0.0f || xf > 63.0f) continue;
      acc += wx * wy * src[yi * 64 + (int)xf];
    }
  }
  warped[g] = acc;
}

// ---------------- per-pixel similarity -> softmax alpha ----------------
__global__ __launch_bounds__(256)
void k_alpha(const float* __restrict__ warped, const float* __restrict__ nam,
             float* __restrict__ alpha) {
  int g = blockIdx.x * 256 + threadIdx.x;   // B*PIX = 8192
  int b = g >> 12, p = g & 4095;
  const float* wbase = warped + (size_t)b * 5 * 128 * PIX + p;
  float dot[5] = {0,0,0,0,0}, ssq[5] = {0,0,0,0,0};
  for (int c = 0; c < 128; ++c) {
    float w0 = wbase[(size_t)c * PIX];
    ssq[0] += w0 * w0;
    #pragma unroll
    for (int k = 1; k < 5; ++k) {
      float wk = wbase[((size_t)k * 128 + c) * PIX];
      dot[k] += w0 * wk;
      ssq[k] += wk * wk;
    }
  }
  dot[0] = ssq[0];
  float n0 = fmaxf(sqrtf(ssq[0]), 1e-6f);
  float logit[5];
  #pragma unroll
  for (int k = 0; k < 5; ++k) {
    float nk = fmaxf(sqrtf(ssq[k]), 1e-6f);
    float sim = dot[k] / (n0 * nk);
    sim = fminf(fmaxf(sim, -1.0f), 1.0f);
    float r = fmaxf(1.0f - sim, 0.0f);
    float xr = r * (1.0f / 0.3f);
    float tt = fmaxf(1.0f - xr * xr, 0.0f);
    float wp = fmaxf(tt * tt, 1e-6f);
    const float* th = nam + (size_t)(b * 25 + k) * 6;
    float tx = th[2], ty = th[5];
    float yaw = fabsf(atan2f(th[1], th[0]));
    float gk = 1.0f / (1.0f + __expf(-(2.0f - 0.4f * sqrtf(tx*tx + ty*ty) - 0.8f * yaw)));
    logit[k] = __logf(wp + 1e-8f) + __logf(gk + 1e-8f);
  }
  float m = logit[0];
  #pragma unroll
  for (int k = 1; k < 5; ++k) m = fmaxf(m, logit[k]);
  float e[5], s = 0.0f;
  #pragma unroll
  for (int k = 0; k < 5; ++k) { e[k] = __expf(logit[k] - m); s += e[k]; }
  float inv = 1.0f / s;
  #pragma unroll
  for (int k = 0; k < 5; ++k)
    alpha[((size_t)(b * 5 + k)) * PIX + p] = e[k] * inv;
}

// ------------- transpose warped*alpha -> tokens_t[b*LL+z][c] -------------
__global__ __launch_bounds__(256)
void k_tokens(const float* __restrict__ warped, const float* __restrict__ alpha,
              float* __restrict__ tok) {
  __shared__ float tl[128][65];
  int blk = blockIdx.x;        // (b*5+a)*64 + ptile
  int pt = blk & 63, ba = blk >> 6;
  int p0 = pt * 64;
  int t = threadIdx.x;
  const float* wsrc = warped + (size_t)ba * 128 * PIX + p0;
  for (int i = 0; i < 32; ++i) {
    int idx = i * 256 + t;
    tl[idx >> 6][idx & 63] = wsrc[(size_t)(idx >> 6) * PIX + (idx & 63)];
  }
  __syncthreads();
  const float* al = alpha + (size_t)ba * PIX + p0;
  float* dst = tok + ((size_t)ba * PIX + p0) * 128;  // ba*4096+p == b*LL + z
  for (int i = 0; i < 32; ++i) {
    int idx = i * 256 + t;
    int p = idx >> 7, c = idx & 127;
    dst[(size_t)p * 128 + c] = tl[c][p] * al[p];
  }
}

// ---------------- generic small GEMM: O = X(rows x128) * W^T ----------------
template<int M, int ZMODE>
__global__ __launch_bounds__(256)
void k_gemm(const float* __restrict__ X, const float* __restrict__ W,
            float* __restrict__ O) {
  constexpr int MG = M / 4;
  __shared__ float xl[64][129];
  __shared__ float wl[M][32];
  int t = threadIdx.x;
  int row0 = blockIdx.x * 64;
  int zl = t & 63, mg = t >> 6;
  for (int i = 0; i < 32; ++i) {
    int idx = i * 256 + t;
    xl[idx >> 7][idx & 127] = X[(size_t)(row0 + (idx >> 7)) * 128 + (idx & 127)];
  }
  float acc[MG];
  #pragma unroll
  for (int i = 0; i < MG; ++i) acc[i] = 0.0f;
  for (int c0 = 0; c0 < 128; c0 += 32) {
    __syncthreads();
    for (int i = t; i < M * 32; i += 256)
      wl[i >> 5][i & 31] = W[(size_t)(i >> 5) * 128 + c0 + (i & 31)];
    __syncthreads();
    for (int cc = 0; cc < 32; ++cc) {
      float xv = xl[zl][c0 + cc];
      #pragma unroll
      for (int mm = 0; mm < MG; ++mm)
        acc[mm] += wl[mg * MG + mm][cc] * xv;
    }
  }
  int row = row0 + zl;
  if (ZMODE == 0) {
    #pragma unroll
    for (int mm = 0; mm < MG; ++mm)
      O[(size_t)row * M + mg * MG + mm] = acc[mm];
  } else {
    int b = row / LL, z = row - b * LL;   // mg == direction k, mm == c (MG=40)
    float* dst = O + ((size_t)(b * 4 + mg) * LL + z) * 40;
    #pragma unroll
    for (int mm = 0; mm < MG; ++mm) dst[mm] = acc[mm];
  }
}

// ---------------- depthwise 3x3 conv over (a=5, p=4096) + SiLU ----------------
__global__ __launch_bounds__(256)
void k_conv(const float* __restrict__ X0, const float* __restrict__ cw,
            const float* __restrict__ cb, float* __restrict__ XT) {
  int g = blockIdx.x * 256 + threadIdx.x;   // B*LL*128 = 5,242,880
  int d = g & 127;
  int zz = g >> 7;           // b*LL + z
  int b = zz / LL, z = zz - b * LL;
  int a = z >> 12, p = z & 4095;
  float acc = cb[d];
  #pragma unroll
  for (int di = 0; di < 3; ++di) {
    int aa = a + di - 1;
    if (aa < 0 || aa >= 5) continue;
    #pragma unroll
    for (int dj = 0; dj < 3; ++dj) {
      int pp = p + dj - 1;
      if (pp < 0 || pp >= PIX) continue;
      acc += cw[d * 9 + di * 3 + dj] * X0[((size_t)b * LL + aa * PIX + pp) * 128 + d];
    }
  }
  float sg = 1.0f / (1.0f + __expf(-acc));
  XT[g] = acc * sg;
}

// ---------------- chunked selective scan (pass1 local / pass3 replay) ----------------
template<int PASS>
__global__ __launch_bounds__(64)
void k_scan(const float* __restrict__ XT, const float* __restrict__ Z,
            const float* __restrict__ dt_w, const float* __restrict__ dt_b,
            const float* __restrict__ A_logs, const float* __restrict__ Ds,
            float* __restrict__ h_out, float* __restrict__ sumdts,
            const float* __restrict__ h_in, float* __restrict__ ysz) {
  constexpr int NCOLS = (PASS == 1) ? 24 : 40;
  constexpr int NSTG = SUBS * NCOLS / 64;
  __shared__ float st[SUBS * 40];
  int bid = blockIdx.x;                 // B*4*2*NCHK = 2048
  int chunk = bid & (NCHK - 1);
  int dh = (bid >> 7) & 1;
  int k  = (bid >> 8) & 3;
  int b  = bid >> 10;
  int lane = threadIdx.x;
  int d = dh * 64 + lane;
  int kd = k * 128 + d;
  float An[NS];
  #pragma unroll
  for (int n = 0; n < NS; ++n) An[n] = -__expf(A_logs[(size_t)kd * 16 + n]);
  float dw[RR];
  #pragma unroll
  for (int r = 0; r < RR; ++r) dw[r] = dt_w[(size_t)kd * 8 + r];
  float dtb = dt_b[kd];
  float dsv = Ds[kd];
  float h[NS];
  if (PASS == 1) {
    #pragma unroll
    for (int n = 0; n < NS; ++n) h[n] = 0.0f;
  } else {
    const float* hi = h_in + (((size_t)(b * 4 + k) * NCHK + chunk) * 128 + d) * 16;
    #pragma unroll
    for (int n = 0; n < NS; ++n) h[n] = hi[n];
  }
  float sdt = 0.0f;
  const float* Zk = Z + (size_t)(b * 4 + k) * LL * 40;
  const float* Xb = XT + (size_t)b * LL * 128;
  float* ysb = ysz + (size_t)(b * 4 + k) * PIX * 128;
  int l0 = chunk * LC;
  for (int sub = 0; sub < NSUB; ++sub) {
    int ls = l0 + sub * SUBS;
    __syncthreads();
    #pragma unroll
    for (int i = 0; i < NSTG; ++i) {
      int idx = i * 64 + lane;
      int s = idx / NCOLS;
      int c = idx - s * NCOLS;
      int l = ls + s;
      int z;
      if (k == 0)      z = l;
      else if (k == 1) z = (l % 5) * 4096 + l / 5;
      else if (k == 2) z = 20479 - l;
      else { int lr = 20479 - l; z = (lr % 5) * 4096 + lr / 5; }
      st[s * NCOLS + c] = Zk[(size_t)z * 40 + c];
    }
    __syncthreads();
    int l = ls;
    int m5 = 0, q5 = 0;
    if (k == 1) { m5 = l % 5; q5 = l / 5; }
    else if (k == 3) { int lr = 20479 - l; m5 = lr % 5; q5 = lr / 5; }
    for (int s = 0; s < SUBS; ++s) {
      int z;
      if (k == 0)      z = l;
      else if (k == 2) z = 20479 - l;
      else             z = m5 * 4096 + q5;
      const float* row = st + s * NCOLS;
      float d0 = dtb + dw[0]*row[0] + dw[1]*row[1] + dw[2]*row[2] + dw[3]*row[3];
      float d1 = dw[4]*row[4] + dw[5]*row[5] + dw[6]*row[6] + dw[7]*row[7];
      float dtl = d0 + d1;
      float dt = (dtl > 20.0f) ? dtl : log1pf(__expf(dtl));   // softplus
      float xv = Xb[(size_t)z * 128 + d];
      float dtx = dt * xv;
      if (PASS == 1) sdt += dt;
      float y0 = 0.f, y1 = 0.f, y2 = 0.f, y3 = 0.f;
      #pragma unroll
      for (int n = 0; n < NS; ++n) {
        float e = __expf(dt * An[n]);
        h[n] = h[n] * e + dtx * row[8 + n];
        if (PASS == 3) {
          float pv = h[n] * row[24 + n];
          if ((n & 3) == 0) y0 += pv;
          else if ((n & 3) == 1) y1 += pv;
          else if ((n & 3) == 2) y2 += pv;
          else y3 += pv;
        }
      }
      if (PASS == 3 && z < PIX)
        ysb[(size_t)z * 128 + d] = (y0 + y1) + (y2 + y3) + dsv * xv;
      ++l;
      if (k == 1) { if (++m5 == 5) { m5 = 0; ++q5; } }
      else if (k == 3) { if (--m5 < 0) { m5 = 4; --q5; } }
    }
  }
  if (PASS == 1) {
    float* ho = h_out + (((size_t)(b * 4 + k) * NCHK + chunk) * 128 + d) * 16;
    #pragma unroll
    for (int n = 0; n < NS; ++n) ho[n] = h[n];
    sumdts[((size_t)(b * 4 + k) * NCHK + chunk) * 128 + d] = sdt;
  }
}

// ---------------- sequential chunk combine ----------------
__global__ __launch_bounds__(256)
void k_combine(const float* __restrict__ A_logs, const float* __restrict__ sumdts,
               const float* __restrict__ h_out, float* __restrict__ h_in) {
  int g = blockIdx.x * 256 + threadIdx.x;   // B*4*128*16 = 16384
  int n = g & 15;
  int d = (g >> 4) & 127;
  int k = (g >> 11) & 3;
  int b = g >> 13;
  float An = -__expf(A_logs[(size_t)(k * 128 + d) * 16 + n]);
  float h = 0.0f;
  size_t base = (size_t)(b * 4 + k) * NCHK * 128;
  for (int j = 0; j < NCHK; ++j) {
    h_in[(base + (size_t)j * 128 + d) * 16 + n] = h;
    float ap = __expf(An * sumdts[base + (size_t)j * 128 + d]);
    h = h * ap + h_out[(base + (size_t)j * 128 + d) * 16 + n];
  }
}

// ---------------- transpose out_proj_w ----------------
__global__ __launch_bounds__(256)
void k_wt(const float* __restrict__ Wo, float* __restrict__ WT) {
  __shared__ float tl[32][33];
  int bx = blockIdx.x & 3, by = blockIdx.x >> 2;
  int t = threadIdx.x;
  int tx = t & 31, ty = t >> 5;
  #pragma unroll
  for (int i = 0; i < 4; ++i)
    tl[ty + i * 8][tx] = Wo[(size_t)(by * 32 + ty + i * 8) * 128 + bx * 32 + tx];
  __syncthreads();
  #pragma unroll
  for (int i = 0; i < 4; ++i)
    WT[(size_t)(bx * 32 + ty + i * 8) * 128 + by * 32 + tx] = tl[tx][ty + i * 8];
}

// ---------------- merge 4 directions + LayerNorm + out_proj ----------------
__global__ __launch_bounds__(128)
void k_merge(const float* __restrict__ ysz, const float* __restrict__ ln_g,
             const float* __restrict__ ln_b, const float* __restrict__ WT,
             float* __restrict__ out) {
  __shared__ float yn[16][129];
  __shared__ float red[4];
  int blk = blockIdx.x;          // B*PIX/16 = 512
  int b = blk >> 8;
  int p0 = (blk & 255) * 16;
  int t = threadIdx.x;
  float g = ln_g[t], bb = ln_b[t];
  const float* yb = ysz + (size_t)b * 4 * PIX * 128;
  for (int pl = 0; pl < 16; ++pl) {
    int p = p0 + pl;
    float y = yb[((size_t)0 * PIX + p) * 128 + t]
            + yb[((size_t)1 * PIX + p) * 128 + t]
            + yb[((size_t)2 * PIX + p) * 128 + t]
            + yb[((size_t)3 * PIX + p) * 128 + t];
    float s1 = y, s2 = y * y;
    #pragma unroll
    for (int off = 32; off; off >>= 1) {
      s1 += __shfl_xor(s1, off);
      s2 += __shfl_xor(s2, off);
    }
    if ((t & 63) == 0) { red[(t >> 6) * 2] = s1; red[(t >> 6) * 2 + 1] = s2; }
    __syncthreads();
    float S1 = red[0] + red[2], S2 = red[1] + red[3];
    float mu = S1 * (1.0f / 128.0f);
    float var = S2 * (1.0f / 128.0f) - mu * mu;
    float rs = rsqrtf(var + 1e-5f);
    yn[pl][t] = (y - mu) * rs * g + bb;
    __syncthreads();
  }
  float acc[16];
  #pragma unroll
  for (int i = 0; i < 16; ++i) acc[i] = 0.0f;
  for (int dd = 0; dd < 128; ++dd) {
    float w = WT[(size_t)dd * 128 + t];
    #pragma unroll
    for (int pl = 0; pl < 16; ++pl)
      acc[pl] += yn[pl][dd] * w;
  }
  __syncthreads();
  #pragma unroll
  for (int pl = 0; pl < 16; ++pl) yn[pl][t] = acc[pl];
  __syncthreads();
  #pragma unroll
  for (int i = 0; i < 16; ++i) {
    int c = i * 8 + (t >> 4);
    int pl = t & 15;
    out[((size_t)b * 128 + c) * PIX + p0 + pl] = yn[pl][c];
  }
}

extern "C" void kernel_launch(void* const* d_in, const int* in_sizes, int n_in,
                              void* d_out, int out_size, void* d_ws, size_t ws_size,
                              hipStream_t stream) {
  const float* x         = (const float*)d_in[0];
  // d_in[1] record_len unused
  const float* nam       = (const float*)d_in[2];
  const float* in_proj_w = (const float*)d_in[3];
  const float* conv_w    = (const float*)d_in[4];
  const float* conv_b    = (const float*)d_in[5];
  const float* x_proj_w  = (const float*)d_in[6];
  const float* dt_w      = (const float*)d_in[7];
  const float* dt_b      = (const float*)d_in[8];
  const float* A_logs    = (const float*)d_in[9];
  const float* Ds        = (const float*)d_in[10];
  const float* ln_g      = (const float*)d_in[11];
  const float* ln_b      = (const float*)d_in[12];
  const float* out_proj_w= (const float*)d_in[13];
  float* out = (float*)d_out;
  float* ws  = (float*)d_ws;

  // workspace layout (floats); total ~36.1M floats (~145 MB)
  float* warped = ws;                          // 5,242,880
  float* alpha  = warped + 5242880;            //    40,960
  float* tok    = alpha  + 40960;              // 5,242,880
  float* X0     = tok    + 5242880;            // 5,242,880
  float* XT     = X0     + 5242880;            // 5,242,880
  float* Z      = XT     + 5242880;            // 6,553,600
  float* h_out  = Z      + 6553600;            // 2,097,152
  float* h_in   = h_out  + 2097152;            // 2,097,152
  float* sums   = h_in   + 2097152;            //   131,072
  float* ysz    = sums   + 131072;             // 4,194,304
  float* WT     = ysz    + 4194304;            //    16,384

  k_warp  <<<20480, 256, 0, stream>>>(x, nam, warped);
  k_alpha <<<32,    256, 0, stream>>>(warped, nam, alpha);
  k_tokens<<<640,   256, 0, stream>>>(warped, alpha, tok);
  k_gemm<128, 0><<<640, 256, 0, stream>>>(tok, in_proj_w, X0);
  k_conv  <<<20480, 256, 0, stream>>>(X0, conv_w, conv_b, XT);
  k_gemm<160, 1><<<640, 256, 0, stream>>>(XT, x_proj_w, Z);
  k_scan<1><<<2048, 64, 0, stream>>>(XT, Z, dt_w, dt_b, A_logs, Ds,
                                     h_out, sums, nullptr, nullptr);
  k_combine<<<64, 256, 0, stream>>>(A_logs, sums, h_out, h_in);
  k_scan<3><<<2048, 64, 0, stream>>>(XT, Z, dt_w, dt_b, A_logs, Ds,
                                     nullptr, nullptr, h_in, ysz);
  k_wt    <<<16,  256, 0, stream>>>(out_proj_w, WT);
  k_merge <<<512, 128, 0, stream>>>(ysz, ln_g, ln_b, WT, out);
}

// Round 2
// 403.852 us; speedup vs baseline: 1.6539x; 1.6539x over previous
//
#include <hip/hip_runtime.h>
#include <math.h>

#define B_S   2
#define PIX   4096
#define LL    20480
#define NS    16
#define RR    8
#define NCHK  256     // chunks per sequence
#define LC    80      // steps per chunk
#define SUBS  20      // steps per LDS staging sub-chunk
#define NSUB  4       // LC/SUBS

__device__ __forceinline__ int zmap(int k, int l) {
  if (k == 0) return l;
  if (k == 1) return (l % 5) * 4096 + l / 5;
  if (k == 2) return 20479 - l;
  int lr = 20479 - l;
  return (lr % 5) * 4096 + lr / 5;
}

// ---------------- affine grid + bilinear grid_sample ----------------
__global__ __launch_bounds__(256)
void k_warp(const float* __restrict__ x, const float* __restrict__ nam,
            float* __restrict__ warped) {
  int g = blockIdx.x * 256 + threadIdx.x;        // B*K*C*PIX = 5,242,880
  int p  = g & 4095;
  int c  = (g >> 12) & 127;
  int bk = g >> 19;                              // 0..9
  int b = bk / 5, k = bk - b * 5;
  const float* th = nam + (size_t)(b * 25 + k) * 6;   // nam[b,0,k]
  float gx = ((p & 63) + 0.5f) * 0.03125f - 1.0f;
  float gy = ((p >> 6) + 0.5f) * 0.03125f - 1.0f;
  float grx = th[0] * gx + th[1] * gy + th[2];
  float gry = th[3] * gx + th[4] * gy + th[5];
  float ix = ((grx + 1.0f) * 64.0f - 1.0f) * 0.5f;
  float iy = ((gry + 1.0f) * 64.0f - 1.0f) * 0.5f;
  float x0 = floorf(ix), y0 = floorf(iy);
  float fx = ix - x0,  fy = iy - y0;
  const float* src = x + (size_t)(bk * 128 + c) * PIX;
  float acc = 0.0f;
  #pragma unroll
  for (int dy = 0; dy < 2; ++dy) {
    float yf = y0 + dy;
    float wy = dy ? fy : 1.0f - fy;
    if (yf < 0.0f || yf > 63.0f) continue;
    int yi = (int)yf;
    #pragma unroll
    for (int dx = 0; dx < 2; ++dx) {
      float xf = x0 + dx;
      float wx = dx ? fx : 1.0f - fx;
      if (xf < 0.0f || xf > 63.0f) continue;
      acc += wx * wy * src[yi * 64 + (int)xf];
    }
  }
  warped[g] = acc;
}

// ---------------- per-pixel similarity -> softmax alpha ----------------
__global__ __launch_bounds__(256)
void k_alpha(const float* __restrict__ warped, const float* __restrict__ nam,
             float* __restrict__ alpha) {
  int g = blockIdx.x * 256 + threadIdx.x;   // B*PIX = 8192
  int b = g >> 12, p = g & 4095;
  const float* wbase = warped + (size_t)b * 5 * 128 * PIX + p;
  float dot[5] = {0,0,0,0,0}, ssq[5] = {0,0,0,0,0};
  for (int c = 0; c < 128; ++c) {
    float w0 = wbase[(size_t)c * PIX];
    ssq[0] += w0 * w0;
    #pragma unroll
    for (int k = 1; k < 5; ++k) {
      float wk = wbase[((size_t)k * 128 + c) * PIX];
      dot[k] += w0 * wk;
      ssq[k] += wk * wk;
    }
  }
  dot[0] = ssq[0];
  float n0 = fmaxf(sqrtf(ssq[0]), 1e-6f);
  float logit[5];
  #pragma unroll
  for (int k = 0; k < 5; ++k) {
    float nk = fmaxf(sqrtf(ssq[k]), 1e-6f);
    float sim = dot[k] / (n0 * nk);
    sim = fminf(fmaxf(sim, -1.0f), 1.0f);
    float r = fmaxf(1.0f - sim, 0.0f);
    float xr = r * (1.0f / 0.3f);
    float tt = fmaxf(1.0f - xr * xr, 0.0f);
    float wp = fmaxf(tt * tt, 1e-6f);
    const float* th = nam + (size_t)(b * 25 + k) * 6;
    float tx = th[2], ty = th[5];
    float yaw = fabsf(atan2f(th[1], th[0]));
    float gk = 1.0f / (1.0f + __expf(-(2.0f - 0.4f * sqrtf(tx*tx + ty*ty) - 0.8f * yaw)));
    logit[k] = __logf(wp + 1e-8f) + __logf(gk + 1e-8f);
  }
  float m = logit[0];
  #pragma unroll
  for (int k = 1; k < 5; ++k) m = fmaxf(m, logit[k]);
  float e[5], s = 0.0f;
  #pragma unroll
  for (int k = 0; k < 5; ++k) { e[k] = __expf(logit[k] - m); s += e[k]; }
  float inv = 1.0f / s;
  #pragma unroll
  for (int k = 0; k < 5; ++k)
    alpha[((size_t)(b * 5 + k)) * PIX + p] = e[k] * inv;
}

// ------------- transpose warped*alpha -> tokens_t[b*LL+z][c] -------------
__global__ __launch_bounds__(256)
void k_tokens(const float* __restrict__ warped, const float* __restrict__ alpha,
              float* __restrict__ tok) {
  __shared__ float tl[128][65];
  int blk = blockIdx.x;        // (b*5+a)*64 + ptile
  int pt = blk & 63, ba = blk >> 6;
  int p0 = pt * 64;
  int t = threadIdx.x;
  const float* wsrc = warped + (size_t)ba * 128 * PIX + p0;
  for (int i = 0; i < 32; ++i) {
    int idx = i * 256 + t;
    tl[idx >> 6][idx & 63] = wsrc[(size_t)(idx >> 6) * PIX + (idx & 63)];
  }
  __syncthreads();
  const float* al = alpha + (size_t)ba * PIX + p0;
  float* dst = tok + ((size_t)ba * PIX + p0) * 128;  // ba*4096+p == b*LL + z
  for (int i = 0; i < 32; ++i) {
    int idx = i * 256 + t;
    int p = idx >> 7, c = idx & 127;
    dst[(size_t)p * 128 + c] = tl[c][p] * al[p];
  }
}

// ---------------- generic small GEMM: O = X(rows x128) * W^T ----------------
// ZMODE==1 writes x_proj output permuted into per-direction scan order.
template<int M, int ZMODE>
__global__ __launch_bounds__(256)
void k_gemm(const float* __restrict__ X, const float* __restrict__ W,
            float* __restrict__ O) {
  constexpr int MG = M / 4;
  __shared__ float xl[64][129];
  __shared__ float wl[M][32];
  int t = threadIdx.x;
  int row0 = blockIdx.x * 64;
  int zl = t & 63, mg = t >> 6;
  for (int i = 0; i < 32; ++i) {
    int idx = i * 256 + t;
    xl[idx >> 7][idx & 127] = X[(size_t)(row0 + (idx >> 7)) * 128 + (idx & 127)];
  }
  float acc[MG];
  #pragma unroll
  for (int i = 0; i < MG; ++i) acc[i] = 0.0f;
  for (int c0 = 0; c0 < 128; c0 += 32) {
    __syncthreads();
    for (int i = t; i < M * 32; i += 256)
      wl[i >> 5][i & 31] = W[(size_t)(i >> 5) * 128 + c0 + (i & 31)];
    __syncthreads();
    for (int cc = 0; cc < 32; ++cc) {
      float xv = xl[zl][c0 + cc];
      #pragma unroll
      for (int mm = 0; mm < MG; ++mm)
        acc[mm] += wl[mg * MG + mm][cc] * xv;
    }
  }
  int row = row0 + zl;
  if (ZMODE == 0) {
    #pragma unroll
    for (int mm = 0; mm < MG; ++mm)
      O[(size_t)row * M + mg * MG + mm] = acc[mm];
  } else {
    int b = row / LL, z = row - b * LL;   // mg == direction k, mm == col (MG=40)
    int a = z >> 12;           // z / 4096
    int q = z & 4095;
    int l;
    if (mg == 0)      l = z;
    else if (mg == 1) l = 5 * q + a;
    else if (mg == 2) l = 20479 - z;
    else              l = 20479 - (5 * q + a);
    float* dst = O + ((size_t)(b * 4 + mg) * LL + l) * 40;
    #pragma unroll
    for (int mm = 0; mm < MG; ++mm) dst[mm] = acc[mm];
  }
}

// ---------------- depthwise 3x3 conv over (a=5, p=4096) + SiLU ----------------
__global__ __launch_bounds__(256)
void k_conv(const float* __restrict__ X0, const float* __restrict__ cw,
            const float* __restrict__ cb, float* __restrict__ XT) {
  int g = blockIdx.x * 256 + threadIdx.x;   // B*LL*128 = 5,242,880
  int d = g & 127;
  int zz = g >> 7;           // b*LL + z
  int b = zz / LL, z = zz - b * LL;
  int a = z >> 12, p = z & 4095;
  float acc = cb[d];
  #pragma unroll
  for (int di = 0; di < 3; ++di) {
    int aa = a + di - 1;
    if (aa < 0 || aa >= 5) continue;
    #pragma unroll
    for (int dj = 0; dj < 3; ++dj) {
      int pp = p + dj - 1;
      if (pp < 0 || pp >= PIX) continue;
      acc += cw[d * 9 + di * 3 + dj] * X0[((size_t)b * LL + aa * PIX + pp) * 128 + d];
    }
  }
  float sg = 1.0f / (1.0f + __expf(-acc));
  XT[g] = acc * sg;
}

// ------- single-pass chunked selective scan: local h + y_partial + cumdt -------
__global__ __launch_bounds__(64, 4)
void k_scan1(const float* __restrict__ XT, const float* __restrict__ Zs,
             const float* __restrict__ dt_w, const float* __restrict__ dt_b,
             const float* __restrict__ A_logs, const float* __restrict__ Ds,
             float* __restrict__ h_out, float* __restrict__ sumdts,
             float* __restrict__ ysz, float* __restrict__ cumdtv) {
  __shared__ __align__(16) float st[SUBS * 40];
  __shared__ float xs[SUBS * 64];
  int bid = blockIdx.x;                 // B*4*2*NCHK = 4096
  int chunk = bid & (NCHK - 1);
  int dh = (bid >> 8) & 1;
  int k  = (bid >> 9) & 3;
  int b  = bid >> 11;
  int lane = threadIdx.x;
  int d = dh * 64 + lane;
  int kd = k * 128 + d;
  // detect An == -(n+1): enables exp(dt*An) = exp(-dt)^(n+1) multiply chain
  bool chainok = true;
  #pragma unroll
  for (int n = 0; n < NS; ++n) {
    float An = -__expf(A_logs[(size_t)kd * 16 + n]);
    chainok = chainok && (fabsf(An + (float)(n + 1)) < 3e-5f * (float)(n + 1));
  }
  float dw[RR];
  #pragma unroll
  for (int r = 0; r < RR; ++r) dw[r] = dt_w[(size_t)kd * 8 + r];
  float dtb = dt_b[kd];
  float dsv = Ds[kd];
  float h[NS];
  #pragma unroll
  for (int n = 0; n < NS; ++n) h[n] = 0.0f;
  float sdt = 0.0f;
  const float* Zseq = Zs + (size_t)(b * 4 + k) * LL * 40;
  const float* Xb = XT + (size_t)b * LL * 128;
  float* ysb = ysz    + (size_t)(b * 4 + k) * PIX * 128;
  float* cdb = cumdtv + (size_t)(b * 4 + k) * PIX * 128;
  int l0 = chunk * LC;
  for (int sub = 0; sub < NSUB; ++sub) {
    int ls = l0 + sub * SUBS;
    __syncthreads();
    for (int i = lane; i < SUBS * 40; i += 64)
      st[i] = Zseq[(size_t)ls * 40 + i];
    #pragma unroll
    for (int s = 0; s < SUBS; ++s) {
      int z = zmap(k, ls + s);
      xs[s * 64 + lane] = Xb[(size_t)z * 128 + d];
    }
    __syncthreads();
    int l = ls;
    int m5 = 0, q5 = 0;
    if (k == 1) { m5 = l % 5; q5 = l / 5; }
    else if (k == 3) { int lr = 20479 - l; m5 = lr % 5; q5 = lr / 5; }
    for (int s = 0; s < SUBS; ++s) {
      int z;
      if (k == 0)      z = l;
      else if (k == 2) z = 20479 - l;
      else             z = m5 * 4096 + q5;
      const float4* r4 = (const float4*)(st + s * 40);
      float4 ra = r4[0], rb = r4[1];
      float dtl = dtb + dw[0]*ra.x + dw[1]*ra.y + dw[2]*ra.z + dw[3]*ra.w
                      + dw[4]*rb.x + dw[5]*rb.y + dw[6]*rb.z + dw[7]*rb.w;
      float dt = (dtl > 20.0f) ? dtl : __logf(1.0f + __expf(dtl));   // softplus
      sdt += dt;
      float xv = xs[s * 64 + lane];
      float dtx = dt * xv;
      float4 b0 = r4[2], b1 = r4[3], b2 = r4[4], b3 = r4[5];
      float Bv[NS] = {b0.x,b0.y,b0.z,b0.w, b1.x,b1.y,b1.z,b1.w,
                      b2.x,b2.y,b2.z,b2.w, b3.x,b3.y,b3.z,b3.w};
      float e1 = __expf(-dt);
      if (chainok) {
        float p = e1;
        #pragma unroll
        for (int n = 0; n < NS; ++n) { h[n] = h[n] * p + dtx * Bv[n]; p *= e1; }
      } else {
        #pragma unroll
        for (int n = 0; n < NS; ++n) {
          float An = -__expf(A_logs[(size_t)kd * 16 + n]);
          h[n] = h[n] * __expf(dt * An) + dtx * Bv[n];
        }
      }
      if (z < PIX) {
        float4 c0 = r4[6], c1 = r4[7], c2 = r4[8], c3 = r4[9];
        float Cv[NS] = {c0.x,c0.y,c0.z,c0.w, c1.x,c1.y,c1.z,c1.w,
                        c2.x,c2.y,c2.z,c2.w, c3.x,c3.y,c3.z,c3.w};
        float y0 = 0.f, y1 = 0.f, y2 = 0.f, y3 = 0.f;
        #pragma unroll
        for (int n = 0; n < NS; n += 4) {
          y0 += h[n] * Cv[n]; y1 += h[n+1] * Cv[n+1];
          y2 += h[n+2] * Cv[n+2]; y3 += h[n+3] * Cv[n+3];
        }
        size_t o = (size_t)z * 128 + d;
        ysb[o] = (y0 + y1) + (y2 + y3) + dsv * xv;
        cdb[o] = sdt;
      }
      ++l;
      if (k == 1) { if (++m5 == 5) { m5 = 0; ++q5; } }
      else if (k == 3) { if (--m5 < 0) { m5 = 4; --q5; } }
    }
  }
  float* ho = h_out + (((size_t)(b * 4 + k) * NCHK + chunk) * 128 + d) * 16;
  #pragma unroll
  for (int n = 0; n < NS; ++n) ho[n] = h[n];
  sumdts[((size_t)(b * 4 + k) * NCHK + chunk) * 128 + d] = sdt;
}

// ---------------- sequential chunk combine ----------------
__global__ __launch_bounds__(256)
void k_combine(const float* __restrict__ A_logs, const float* __restrict__ sumdts,
               const float* __restrict__ h_out, float* __restrict__ h_in) {
  int g = blockIdx.x * 256 + threadIdx.x;   // B*4*128*16 = 16384
  int n = g & 15;
  int d = (g >> 4) & 127;
  int k = (g >> 11) & 3;
  int b = g >> 13;
  float An = -__expf(A_logs[(size_t)(k * 128 + d) * 16 + n]);
  float h = 0.0f;
  size_t base = (size_t)(b * 4 + k) * NCHK * 128;
  for (int j = 0; j < NCHK; ++j) {
    h_in[(base + (size_t)j * 128 + d) * 16 + n] = h;
    float ap = __expf(An * sumdts[base + (size_t)j * 128 + d]);
    h = h * ap + h_out[(base + (size_t)j * 128 + d) * 16 + n];
  }
}

// ------------- add cross-chunk correction: y += C · (E(l)·h_in) -------------
__global__ __launch_bounds__(256)
void k_fixup(const float* __restrict__ Zs, const float* __restrict__ A_logs,
             const float* __restrict__ h_in, const float* __restrict__ cumdtv,
             float* __restrict__ ysz) {
  int g = blockIdx.x * 256 + threadIdx.x;   // B*4*PIX*128 = 4,194,304
  int d = g & 127;
  int z = (g >> 7) & 4095;
  int k = (g >> 19) & 3;
  int b = g >> 21;
  int l;
  if (k == 0)      l = z;
  else if (k == 1) l = 5 * z;
  else if (k == 2) l = 20479 - z;
  else             l = 20479 - 5 * z;
  int chunk = l / LC;
  int kd = k * 128 + d;
  float cd = cumdtv[g];
  const float* hi = h_in + (((size_t)(b * 4 + k) * NCHK + chunk) * 128 + d) * 16;
  const float* Crow = Zs + ((size_t)(b * 4 + k) * LL + l) * 40 + 24;
  float acc = 0.0f;
  #pragma unroll
  for (int n = 0; n < NS; ++n) {
    float An = -__expf(A_logs[(size_t)kd * 16 + n]);
    acc += Crow[n] * hi[n] * __expf(An * cd);
  }
  ysz[g] += acc;
}

// ---------------- transpose out_proj_w ----------------
__global__ __launch_bounds__(256)
void k_wt(const float* __restrict__ Wo, float* __restrict__ WT) {
  __shared__ float tl[32][33];
  int bx = blockIdx.x & 3, by = blockIdx.x >> 2;
  int t = threadIdx.x;
  int tx = t & 31, ty = t >> 5;
  #pragma unroll
  for (int i = 0; i < 4; ++i)
    tl[ty + i * 8][tx] = Wo[(size_t)(by * 32 + ty + i * 8) * 128 + bx * 32 + tx];
  __syncthreads();
  #pragma unroll
  for (int i = 0; i < 4; ++i)
    WT[(size_t)(bx * 32 + ty + i * 8) * 128 + by * 32 + tx] = tl[tx][ty + i * 8];
}

// ---------------- merge 4 directions + LayerNorm + out_proj ----------------
__global__ __launch_bounds__(128)
void k_merge(const float* __restrict__ ysz, const float* __restrict__ ln_g,
             const float* __restrict__ ln_b, const float* __restrict__ WT,
             float* __restrict__ out) {
  __shared__ float yn[16][129];
  __shared__ float red[4];
  int blk = blockIdx.x;          // B*PIX/16 = 512
  int b = blk >> 8;
  int p0 = (blk & 255) * 16;
  int t = threadIdx.x;
  float g = ln_g[t], bb = ln_b[t];
  const float* yb = ysz + (size_t)b * 4 * PIX * 128;
  for (int pl = 0; pl < 16; ++pl) {
    int p = p0 + pl;
    float y = yb[((size_t)0 * PIX + p) * 128 + t]
            + yb[((size_t)1 * PIX + p) * 128 + t]
            + yb[((size_t)2 * PIX + p) * 128 + t]
            + yb[((size_t)3 * PIX + p) * 128 + t];
    float s1 = y, s2 = y * y;
    #pragma unroll
    for (int off = 32; off; off >>= 1) {
      s1 += __shfl_xor(s1, off);
      s2 += __shfl_xor(s2, off);
    }
    if ((t & 63) == 0) { red[(t >> 6) * 2] = s1; red[(t >> 6) * 2 + 1] = s2; }
    __syncthreads();
    float S1 = red[0] + red[2], S2 = red[1] + red[3];
    float mu = S1 * (1.0f / 128.0f);
    float var = S2 * (1.0f / 128.0f) - mu * mu;
    float rs = rsqrtf(var + 1e-5f);
    yn[pl][t] = (y - mu) * rs * g + bb;
    __syncthreads();
  }
  float acc[16];
  #pragma unroll
  for (int i = 0; i < 16; ++i) acc[i] = 0.0f;
  for (int dd = 0; dd < 128; ++dd) {
    float w = WT[(size_t)dd * 128 + t];
    #pragma unroll
    for (int pl = 0; pl < 16; ++pl)
      acc[pl] += yn[pl][dd] * w;
  }
  __syncthreads();
  #pragma unroll
  for (int pl = 0; pl < 16; ++pl) yn[pl][t] = acc[pl];
  __syncthreads();
  #pragma unroll
  for (int i = 0; i < 16; ++i) {
    int c = i * 8 + (t >> 4);
    int pl = t & 15;
    out[((size_t)b * 128 + c) * PIX + p0 + pl] = yn[pl][c];
  }
}

extern "C" void kernel_launch(void* const* d_in, const int* in_sizes, int n_in,
                              void* d_out, int out_size, void* d_ws, size_t ws_size,
                              hipStream_t stream) {
  const float* x         = (const float*)d_in[0];
  // d_in[1] record_len unused
  const float* nam       = (const float*)d_in[2];
  const float* in_proj_w = (const float*)d_in[3];
  const float* conv_w    = (const float*)d_in[4];
  const float* conv_b    = (const float*)d_in[5];
  const float* x_proj_w  = (const float*)d_in[6];
  const float* dt_w      = (const float*)d_in[7];
  const float* dt_b      = (const float*)d_in[8];
  const float* A_logs    = (const float*)d_in[9];
  const float* Ds        = (const float*)d_in[10];
  const float* ln_g      = (const float*)d_in[11];
  const float* ln_b      = (const float*)d_in[12];
  const float* out_proj_w= (const float*)d_in[13];
  float* out = (float*)d_out;
  float* ws  = (float*)d_ws;

  // workspace layout (floats); total ~32.0M floats (~128 MB)
  float* warped = ws;                          // 5,242,880  (later: h_out 4.2M)
  float* alpha  = warped + 5242880;            //    40,960
  float* tok    = alpha  + 40960;              // 5,242,880  (later: cumdt 4.2M)
  float* X0     = tok    + 5242880;            // 5,242,880  (later: h_in 4.2M)
  float* XT     = X0     + 5242880;            // 5,242,880
  float* Zs     = XT     + 5242880;            // 6,553,600
  float* sums   = Zs     + 6553600;            //   262,144
  float* ysz    = sums   + 262144;             // 4,194,304
  float* WT     = ysz    + 4194304;            //    16,384

  float* h_out = warped;   // warped dead after k_tokens
  float* cumdt = tok;      // tok dead after in_proj gemm
  float* h_in  = X0;       // X0 dead after k_conv

  k_warp  <<<20480, 256, 0, stream>>>(x, nam, warped);
  k_alpha <<<32,    256, 0, stream>>>(warped, nam, alpha);
  k_tokens<<<640,   256, 0, stream>>>(warped, alpha, tok);
  k_gemm<128, 0><<<640, 256, 0, stream>>>(tok, in_proj_w, X0);
  k_conv  <<<20480, 256, 0, stream>>>(X0, conv_w, conv_b, XT);
  k_gemm<160, 1><<<640, 256, 0, stream>>>(XT, x_proj_w, Zs);
  k_scan1 <<<4096, 64, 0, stream>>>(XT, Zs, dt_w, dt_b, A_logs, Ds,
                                    h_out, sums, ysz, cumdt);
  k_combine<<<64, 256, 0, stream>>>(A_logs, sums, h_out, h_in);
  k_fixup <<<16384, 256, 0, stream>>>(Zs, A_logs, h_in, cumdt, ysz);
  k_wt    <<<16,  256, 0, stream>>>(out_proj_w, WT);
  k_merge <<<512, 128, 0, stream>>>(ysz, ln_g, ln_b, WT, out);
}

// Round 3
// 369.085 us; speedup vs baseline: 1.8097x; 1.0942x over previous
//
#include <hip/hip_runtime.h>
#include <math.h>

#define B_S   2
#define PIX   4096
#define LL    20480
#define NS    16
#define RR    8
#define NCHK  256     // chunks per sequence
#define LC    80      // steps per chunk
#define SUBS  20      // steps per staging sub-chunk
#define NSUB  4       // LC/SUBS

template<int K>
__device__ __forceinline__ int zmapT(int l) {
  if (K == 0) return l;
  if (K == 1) return ((l % 5) << 12) + l / 5;
  if (K == 2) return 20479 - l;
  int lr = 20479 - l;
  return ((lr % 5) << 12) + lr / 5;
}

// ---------------- affine grid + bilinear grid_sample ----------------
__global__ __launch_bounds__(256)
void k_warp(const float* __restrict__ x, const float* __restrict__ nam,
            float* __restrict__ warped) {
  int g = blockIdx.x * 256 + threadIdx.x;        // B*K*C*PIX = 5,242,880
  int p  = g & 4095;
  int c  = (g >> 12) & 127;
  int bk = g >> 19;                              // 0..9
  int b = bk / 5, k = bk - b * 5;
  const float* th = nam + (size_t)(b * 25 + k) * 6;   // nam[b,0,k]
  float gx = ((p & 63) + 0.5f) * 0.03125f - 1.0f;
  float gy = ((p >> 6) + 0.5f) * 0.03125f - 1.0f;
  float grx = th[0] * gx + th[1] * gy + th[2];
  float gry = th[3] * gx + th[4] * gy + th[5];
  float ix = ((grx + 1.0f) * 64.0f - 1.0f) * 0.5f;
  float iy = ((gry + 1.0f) * 64.0f - 1.0f) * 0.5f;
  float x0 = floorf(ix), y0 = floorf(iy);
  float fx = ix - x0,  fy = iy - y0;
  const float* src = x + (size_t)(bk * 128 + c) * PIX;
  float acc = 0.0f;
  #pragma unroll
  for (int dy = 0; dy < 2; ++dy) {
    float yf = y0 + dy;
    float wy = dy ? fy : 1.0f - fy;
    if (yf < 0.0f || yf > 63.0f) continue;
    int yi = (int)yf;
    #pragma unroll
    for (int dx = 0; dx < 2; ++dx) {
      float xf = x0 + dx;
      float wx = dx ? fx : 1.0f - fx;
      if (xf < 0.0f || xf > 63.0f) continue;
      acc += wx * wy * src[yi * 64 + (int)xf];
    }
  }
  warped[g] = acc;
}

// ---------------- per-pixel similarity -> softmax alpha ----------------
__global__ __launch_bounds__(256)
void k_alpha(const float* __restrict__ warped, const float* __restrict__ nam,
             float* __restrict__ alpha) {
  __shared__ float part[4][64][9];
  int blk = blockIdx.x;            // 128 blocks
  int b = blk >> 6;
  int p0 = (blk & 63) << 6;
  int wv = threadIdx.x >> 6, lane = threadIdx.x & 63;
  int p = p0 + lane;
  const float* wb = warped + (size_t)b * 5 * 128 * PIX + p;
  float dot[5] = {0,0,0,0,0}, ssq[5] = {0,0,0,0,0};
  int c0 = wv * 32;
  for (int c = c0; c < c0 + 32; ++c) {
    float w0 = wb[(size_t)c * PIX];
    ssq[0] += w0 * w0;
    #pragma unroll
    for (int k = 1; k < 5; ++k) {
      float wk = wb[((size_t)k * 128 + c) * PIX];
      dot[k] += w0 * wk;
      ssq[k] += wk * wk;
    }
  }
  part[wv][lane][0] = ssq[0];
  #pragma unroll
  for (int k = 1; k < 5; ++k) {
    part[wv][lane][k] = dot[k];
    part[wv][lane][4 + k] = ssq[k];
  }
  __syncthreads();
  if (threadIdx.x < 64) {
    float q[9];
    #pragma unroll
    for (int j = 0; j < 9; ++j)
      q[j] = part[0][lane][j] + part[1][lane][j] + part[2][lane][j] + part[3][lane][j];
    float n0 = fmaxf(sqrtf(q[0]), 1e-6f);
    float logit[5];
    #pragma unroll
    for (int k = 0; k < 5; ++k) {
      float dotk = (k == 0) ? q[0] : q[k];
      float ssqk = (k == 0) ? q[0] : q[4 + k];
      float nk = fmaxf(sqrtf(ssqk), 1e-6f);
      float sim = fminf(fmaxf(dotk / (n0 * nk), -1.0f), 1.0f);
      float r = fmaxf(1.0f - sim, 0.0f);
      float xr = r * (1.0f / 0.3f);
      float tt = fmaxf(1.0f - xr * xr, 0.0f);
      float wp = fmaxf(tt * tt, 1e-6f);
      const float* th = nam + (size_t)(b * 25 + k) * 6;
      float tx = th[2], ty = th[5];
      float yaw = fabsf(atan2f(th[1], th[0]));
      float gk = 1.0f / (1.0f + __expf(-(2.0f - 0.4f * sqrtf(tx*tx + ty*ty) - 0.8f * yaw)));
      logit[k] = __logf(wp + 1e-8f) + __logf(gk + 1e-8f);
    }
    float m = logit[0];
    #pragma unroll
    for (int k = 1; k < 5; ++k) m = fmaxf(m, logit[k]);
    float e[5], s = 0.0f;
    #pragma unroll
    for (int k = 0; k < 5; ++k) { e[k] = __expf(logit[k] - m); s += e[k]; }
    float inv = 1.0f / s;
    #pragma unroll
    for (int k = 0; k < 5; ++k)
      alpha[((size_t)(b * 5 + k)) * PIX + p] = e[k] * inv;
  }
}

// ---- in_proj GEMM fused with tokens transpose: X0 = (warped*alpha)^T @ W^T ----
__global__ __launch_bounds__(256, 4)
void k_gemm_in(const float* __restrict__ warped, const float* __restrict__ alpha,
               const float* __restrict__ W, float* __restrict__ X0) {
  __shared__ float xl[64][129];
  __shared__ __align__(16) float wlT[32][132];
  int t = threadIdx.x;
  int row0 = blockIdx.x * 64;             // 640 blocks, rows = b*LL + a*4096 + p
  int b = row0 / LL;
  int z0 = row0 - b * LL;
  int a = z0 >> 12;
  int p0 = z0 & 4095;
  int ba = b * 5 + a;
  int r = t & 63, cg = t >> 6;
  float av = alpha[(size_t)ba * PIX + p0 + r];
  #pragma unroll
  for (int i = 0; i < 32; ++i) {
    int c = cg * 32 + i;
    xl[r][c] = warped[((size_t)ba * 128 + c) * PIX + p0 + r] * av;
  }
  int zl = t & 63, mg = t >> 6;
  float acc[32];
  #pragma unroll
  for (int i = 0; i < 32; ++i) acc[i] = 0.0f;
  for (int c0 = 0; c0 < 128; c0 += 32) {
    __syncthreads();
    #pragma unroll
    for (int i = 0; i < 16; ++i) {
      int m = (t >> 5) * 16 + i;
      wlT[t & 31][m] = W[(size_t)m * 128 + c0 + (t & 31)];
    }
    __syncthreads();
    for (int cc = 0; cc < 32; ++cc) {
      float xv = xl[zl][c0 + cc];
      const float4* wr = (const float4*)(&wlT[cc][mg * 32]);
      #pragma unroll
      for (int q = 0; q < 8; ++q) {
        float4 w4 = wr[q];
        acc[q*4+0] = fmaf(w4.x, xv, acc[q*4+0]);
        acc[q*4+1] = fmaf(w4.y, xv, acc[q*4+1]);
        acc[q*4+2] = fmaf(w4.z, xv, acc[q*4+2]);
        acc[q*4+3] = fmaf(w4.w, xv, acc[q*4+3]);
      }
    }
  }
  __syncthreads();
  #pragma unroll
  for (int q = 0; q < 32; ++q) xl[zl][mg * 32 + q] = acc[q];
  __syncthreads();
  #pragma unroll
  for (int i = 0; i < 32; ++i) {
    int idx = i * 256 + t;
    X0[((size_t)row0 + (idx >> 7)) * 128 + (idx & 127)] = xl[idx >> 7][idx & 127];
  }
}

// ---------------- depthwise 3x3 conv over (a=5, p=4096) + SiLU ----------------
__global__ __launch_bounds__(256)
void k_conv(const float* __restrict__ X0, const float* __restrict__ cw,
            const float* __restrict__ cb, float* __restrict__ XT) {
  int g = blockIdx.x * 256 + threadIdx.x;   // B*LL*128 = 5,242,880
  int d = g & 127;
  int zz = g >> 7;           // b*LL + z
  int b = zz / LL, z = zz - b * LL;
  int a = z >> 12, p = z & 4095;
  float acc = cb[d];
  #pragma unroll
  for (int di = 0; di < 3; ++di) {
    int aa = a + di - 1;
    if (aa < 0 || aa >= 5) continue;
    #pragma unroll
    for (int dj = 0; dj < 3; ++dj) {
      int pp = p + dj - 1;
      if (pp < 0 || pp >= PIX) continue;
      acc += cw[d * 9 + di * 3 + dj] * X0[((size_t)b * LL + aa * PIX + pp) * 128 + d];
    }
  }
  float sg = 1.0f / (1.0f + __expf(-acc));
  XT[g] = acc * sg;
}

// ---- x_proj GEMM, output permuted to scan order, split ZdtB[24] / ZC[16] ----
__global__ __launch_bounds__(256, 4)
void k_gemmZ(const float* __restrict__ X, const float* __restrict__ W,
             float* __restrict__ ZdtB, float* __restrict__ ZC) {
  __shared__ float xl[64][129];
  __shared__ __align__(16) float wlT[32][164];
  int t = threadIdx.x;
  int row0 = blockIdx.x * 64;
  #pragma unroll
  for (int i = 0; i < 32; ++i) {
    int idx = i * 256 + t;
    xl[idx >> 7][idx & 127] = X[((size_t)row0 + (idx >> 7)) * 128 + (idx & 127)];
  }
  int zl = t & 63, mg = t >> 6;
  float acc[40];
  #pragma unroll
  for (int i = 0; i < 40; ++i) acc[i] = 0.0f;
  for (int c0 = 0; c0 < 128; c0 += 32) {
    __syncthreads();
    #pragma unroll
    for (int i = 0; i < 20; ++i) {
      int m = (t >> 5) * 20 + i;
      wlT[t & 31][m] = W[(size_t)m * 128 + c0 + (t & 31)];
    }
    __syncthreads();
    for (int cc = 0; cc < 32; ++cc) {
      float xv = xl[zl][c0 + cc];
      const float4* wr = (const float4*)(&wlT[cc][mg * 40]);
      #pragma unroll
      for (int q = 0; q < 10; ++q) {
        float4 w4 = wr[q];
        acc[q*4+0] = fmaf(w4.x, xv, acc[q*4+0]);
        acc[q*4+1] = fmaf(w4.y, xv, acc[q*4+1]);
        acc[q*4+2] = fmaf(w4.z, xv, acc[q*4+2]);
        acc[q*4+3] = fmaf(w4.w, xv, acc[q*4+3]);
      }
    }
  }
  int row = row0 + zl;
  int b = row / LL, z = row - b * LL;
  int a = z >> 12, qq = z & 4095;
  int l;
  if (mg == 0)      l = z;
  else if (mg == 1) l = 5 * qq + a;
  else if (mg == 2) l = 20479 - z;
  else              l = 20479 - (5 * qq + a);
  float* dD = ZdtB + ((size_t)(b * 4 + mg) * LL + l) * 24;
  #pragma unroll
  for (int q2 = 0; q2 < 6; ++q2) {
    float4 v = make_float4(acc[q2*4], acc[q2*4+1], acc[q2*4+2], acc[q2*4+3]);
    *(float4*)(dD + q2 * 4) = v;
  }
  float* dC = ZC + ((size_t)(b * 4 + mg) * LL + l) * 16;
  #pragma unroll
  for (int q2 = 0; q2 < 4; ++q2) {
    float4 v = make_float4(acc[24+q2*4], acc[24+q2*4+1], acc[24+q2*4+2], acc[24+q2*4+3]);
    *(float4*)(dC + q2 * 4) = v;
  }
}

// ------- single-pass chunked selective scan (per-wave, barrier-free) -------
template<int K>
__device__ void scan_body(int b, int chunk, int dh, int lane,
    const float* __restrict__ XT, const float* __restrict__ ZdtB,
    const float* __restrict__ ZC,
    const float* __restrict__ dt_w, const float* __restrict__ dt_b,
    const float* __restrict__ A_logs, const float* __restrict__ Ds,
    float* __restrict__ h_out, float* __restrict__ sumdts,
    float* __restrict__ ysz, float* __restrict__ cumdtv,
    float* stD, float* stC)
{
  const int d = dh * 64 + lane;
  const int kd = K * 128 + d;
  bool chainok = true;
  #pragma unroll
  for (int n = 0; n < NS; ++n) {
    float An = -__expf(A_logs[(size_t)kd * 16 + n]);
    chainok = chainok && (fabsf(An + (float)(n + 1)) < 3e-5f * (float)(n + 1));
  }
  float dw[RR];
  #pragma unroll
  for (int r = 0; r < RR; ++r) dw[r] = dt_w[(size_t)kd * 8 + r];
  const float dtb = dt_b[kd], dsv = Ds[kd];
  float h[NS];
  #pragma unroll
  for (int n = 0; n < NS; ++n) h[n] = 0.0f;
  float sdt = 0.0f;
  const int seq = b * 4 + K;
  const float* ZDs = ZdtB + (size_t)seq * LL * 24;
  const float* ZCs = ZC + (size_t)seq * LL * 16;
  const float* Xb = XT + (size_t)b * LL * 128;
  float* ysb = ysz + (size_t)seq * PIX * 128;
  float* cdb = cumdtv + (size_t)seq * PIX * 128;
  const int l0 = chunk * LC;

  if (__all(chainok ? 1 : 0)) {
    #pragma unroll 1
    for (int sub = 0; sub < NSUB; ++sub) {
      const int ls = l0 + sub * SUBS;
      // stage dt/B rows (480 floats) via regs -> per-wave LDS (no barrier needed)
      {
        float zr[8];
        #pragma unroll
        for (int i = 0; i < 8; ++i) {
          int idx = i * 64 + lane;
          zr[i] = (idx < SUBS * 24) ? ZDs[(size_t)ls * 24 + idx] : 0.0f;
        }
        #pragma unroll
        for (int i = 0; i < 8; ++i) {
          int idx = i * 64 + lane;
          if (idx < SUBS * 24) stD[idx] = zr[i];
        }
      }
      int s0c = 0;
      bool needC;
      if (K == 0)      needC = (ls < PIX);
      else if (K == 2) needC = (ls + SUBS > LL - PIX);
      else             needC = true;
      if (K == 1) s0c = (5 - (ls % 5)) % 5;
      if (K == 3) s0c = (9 - (ls % 5)) % 5;
      if (needC) {
        if (K == 0 || K == 2) {
          #pragma unroll
          for (int i = 0; i < 5; ++i) {
            int idx = i * 64 + lane;
            stC[idx] = ZCs[(size_t)ls * 16 + idx];
          }
        } else {
          int j = lane >> 4, col = lane & 15;
          int l = ls + s0c + 5 * j;
          stC[lane] = ZCs[(size_t)l * 16 + col];
        }
      }
      // register-stage x for 20 steps
      float xr[SUBS];
      #pragma unroll
      for (int s = 0; s < SUBS; ++s) {
        int z = zmapT<K>(ls + s);
        xr[s] = Xb[(size_t)z * 128 + d];
      }
      int zc = 0;
      if (K == 1) zc = (ls + s0c) / 5;
      if (K == 3) zc = (20479 - ls - s0c) / 5;
      int yj = 0;
      #pragma unroll
      for (int s = 0; s < SUBS; ++s) {
        const float4* rD = (const float4*)(stD + s * 24);
        float4 ra = rD[0], rb4 = rD[1];
        float dtl = dtb;
        dtl = fmaf(dw[0], ra.x, dtl);  dtl = fmaf(dw[1], ra.y, dtl);
        dtl = fmaf(dw[2], ra.z, dtl);  dtl = fmaf(dw[3], ra.w, dtl);
        dtl = fmaf(dw[4], rb4.x, dtl); dtl = fmaf(dw[5], rb4.y, dtl);
        dtl = fmaf(dw[6], rb4.z, dtl); dtl = fmaf(dw[7], rb4.w, dtl);
        float edt = __expf(dtl);
        float e1 = __builtin_amdgcn_rcpf(1.0f + edt);  // exp(-softplus(dtl))
        float dt = (dtl > 20.0f) ? dtl : __logf(1.0f + edt);
        sdt += dt;
        float dtx = dt * xr[s];
        float4 b0 = rD[2], b1 = rD[3], b2 = rD[4], b3 = rD[5];
        float e2 = e1*e1, e4 = e2*e2, e8 = e4*e4;
        float p3 = e2*e1, p5 = e4*e1, p6 = e4*e2, p7 = e4*p3;
        h[0]  = fmaf(h[0],  e1,    dtx*b0.x);
        h[1]  = fmaf(h[1],  e2,    dtx*b0.y);
        h[2]  = fmaf(h[2],  p3,    dtx*b0.z);
        h[3]  = fmaf(h[3],  e4,    dtx*b0.w);
        h[4]  = fmaf(h[4],  p5,    dtx*b1.x);
        h[5]  = fmaf(h[5],  p6,    dtx*b1.y);
        h[6]  = fmaf(h[6],  p7,    dtx*b1.z);
        h[7]  = fmaf(h[7],  e8,    dtx*b1.w);
        h[8]  = fmaf(h[8],  e8*e1, dtx*b2.x);
        h[9]  = fmaf(h[9],  e8*e2, dtx*b2.y);
        h[10] = fmaf(h[10], e8*p3, dtx*b2.z);
        h[11] = fmaf(h[11], e8*e4, dtx*b2.w);
        h[12] = fmaf(h[12], e8*p5, dtx*b3.x);
        h[13] = fmaf(h[13], e8*p6, dtx*b3.y);
        h[14] = fmaf(h[14], e8*p7, dtx*b3.z);
        h[15] = fmaf(h[15], e8*e8, dtx*b3.w);
        bool doY;
        int z;
        if (K == 0)      { z = ls + s;            doY = (z < PIX); }
        else if (K == 2) { z = 20479 - (ls + s);  doY = (z < PIX); }
        else             { z = zc;                doY = ((s % 5) == s0c); }
        if (doY) {
          const float4* rC = (const float4*)(stC + ((K == 0 || K == 2) ? s : yj) * 16);
          float4 c0 = rC[0], c1 = rC[1], c2 = rC[2], c3 = rC[3];
          float y = dsv * xr[s];
          y = fmaf(h[0],  c0.x, y); y = fmaf(h[1],  c0.y, y);
          y = fmaf(h[2],  c0.z, y); y = fmaf(h[3],  c0.w, y);
          y = fmaf(h[4],  c1.x, y); y = fmaf(h[5],  c1.y, y);
          y = fmaf(h[6],  c1.z, y); y = fmaf(h[7],  c1.w, y);
          y = fmaf(h[8],  c2.x, y); y = fmaf(h[9],  c2.y, y);
          y = fmaf(h[10], c2.z, y); y = fmaf(h[11], c2.w, y);
          y = fmaf(h[12], c3.x, y); y = fmaf(h[13], c3.y, y);
          y = fmaf(h[14], c3.z, y); y = fmaf(h[15], c3.w, y);
          size_t o = (size_t)z * 128 + d;
          ysb[o] = y;
          cdb[o] = sdt;
          ++yj;
          if (K == 1) ++zc;
          if (K == 3) --zc;
        }
      }
    }
  } else {
    // general fallback (compact, rarely taken)
    float An[NS];
    #pragma unroll
    for (int n = 0; n < NS; ++n) An[n] = -__expf(A_logs[(size_t)kd * 16 + n]);
    #pragma unroll 1
    for (int l = l0; l < l0 + LC; ++l) {
      int z = zmapT<K>(l);
      const float* rowD = ZDs + (size_t)l * 24;
      float dtl = dtb;
      #pragma unroll
      for (int r = 0; r < RR; ++r) dtl += dw[r] * rowD[r];
      float edt = __expf(dtl);
      float dt = (dtl > 20.0f) ? dtl : __logf(1.0f + edt);
      sdt += dt;
      float xv = Xb[(size_t)z * 128 + d];
      float dtx = dt * xv;
      #pragma unroll
      for (int n = 0; n < NS; ++n)
        h[n] = h[n] * __expf(dt * An[n]) + dtx * rowD[8 + n];
      if (z < PIX) {
        const float* rowC = ZCs + (size_t)l * 16;
        float y = dsv * xv;
        #pragma unroll
        for (int n = 0; n < NS; ++n) y = fmaf(h[n], rowC[n], y);
        size_t o = (size_t)z * 128 + d;
        ysb[o] = y;
        cdb[o] = sdt;
      }
    }
  }
  float* ho = h_out + (((size_t)seq * NCHK + chunk) * 128 + d) * 16;
  #pragma unroll
  for (int n = 0; n < NS; ++n) ho[n] = h[n];
  sumdts[((size_t)seq * NCHK + chunk) * 128 + d] = sdt;
}

__global__ __launch_bounds__(256, 4)
void k_scan1(const float* __restrict__ XT, const float* __restrict__ ZdtB,
             const float* __restrict__ ZC,
             const float* __restrict__ dt_w, const float* __restrict__ dt_b,
             const float* __restrict__ A_logs, const float* __restrict__ Ds,
             float* __restrict__ h_out, float* __restrict__ sumdts,
             float* __restrict__ ysz, float* __restrict__ cumdtv) {
  __shared__ __align__(16) float stD_all[4][SUBS * 24];
  __shared__ __align__(16) float stC_all[4][SUBS * 16];
  int tid = threadIdx.x, wid = tid >> 6, lane = tid & 63;
  int bid = blockIdx.x;            // 1024 = B*4*(NCHK/2)
  int cp = bid & 127;
  int k = (bid >> 7) & 3;
  int b = bid >> 9;
  int chunk = cp * 2 + (wid >> 1);
  int dh = wid & 1;
  float* stD = stD_all[wid];
  float* stC = stC_all[wid];
  switch (k) {
    case 0: scan_body<0>(b, chunk, dh, lane, XT, ZdtB, ZC, dt_w, dt_b, A_logs, Ds, h_out, sumdts, ysz, cumdtv, stD, stC); break;
    case 1: scan_body<1>(b, chunk, dh, lane, XT, ZdtB, ZC, dt_w, dt_b, A_logs, Ds, h_out, sumdts, ysz, cumdtv, stD, stC); break;
    case 2: scan_body<2>(b, chunk, dh, lane, XT, ZdtB, ZC, dt_w, dt_b, A_logs, Ds, h_out, sumdts, ysz, cumdtv, stD, stC); break;
    default: scan_body<3>(b, chunk, dh, lane, XT, ZdtB, ZC, dt_w, dt_b, A_logs, Ds, h_out, sumdts, ysz, cumdtv, stD, stC); break;
  }
}

// ---------------- sequential chunk combine ----------------
__global__ __launch_bounds__(256)
void k_combine(const float* __restrict__ A_logs, const float* __restrict__ sumdts,
               const float* __restrict__ h_out, float* __restrict__ h_in) {
  int g = blockIdx.x * 256 + threadIdx.x;   // B*4*128*16 = 16384
  int n = g & 15;
  int d = (g >> 4) & 127;
  int k = (g >> 11) & 3;
  int b = g >> 13;
  float An = -__expf(A_logs[(size_t)(k * 128 + d) * 16 + n]);
  float h = 0.0f;
  size_t base = (size_t)(b * 4 + k) * NCHK * 128;
  for (int j = 0; j < NCHK; ++j) {
    h_in[(base + (size_t)j * 128 + d) * 16 + n] = h;
    float ap = __expf(An * sumdts[base + (size_t)j * 128 + d]);
    h = h * ap + h_out[(base + (size_t)j * 128 + d) * 16 + n];
  }
}

// ------------- add cross-chunk correction: y += C · (E(l)·h_in) -------------
__global__ __launch_bounds__(256)
void k_fixup(const float* __restrict__ ZC, const float* __restrict__ A_logs,
             const float* __restrict__ h_in, const float* __restrict__ cumdtv,
             float* __restrict__ ysz) {
  int g = blockIdx.x * 256 + threadIdx.x;   // B*4*PIX*128 = 4,194,304
  int d = g & 127;
  int z = (g >> 7) & 4095;
  int k = (g >> 19) & 3;
  int b = g >> 21;
  int l;
  if (k == 0)      l = z;
  else if (k == 1) l = 5 * z;
  else if (k == 2) l = 20479 - z;
  else             l = 20479 - 5 * z;
  int chunk = l / LC;
  int kd = k * 128 + d;
  float cd = cumdtv[g];
  const float* hi = h_in + (((size_t)(b * 4 + k) * NCHK + chunk) * 128 + d) * 16;
  const float* Crow = ZC + ((size_t)(b * 4 + k) * LL + l) * 16;
  float acc = 0.0f;
  #pragma unroll
  for (int n = 0; n < NS; ++n) {
    float An = -__expf(A_logs[(size_t)kd * 16 + n]);
    acc += Crow[n] * hi[n] * __expf(An * cd);
  }
  ysz[g] += acc;
}

// ---------------- transpose out_proj_w ----------------
__global__ __launch_bounds__(256)
void k_wt(const float* __restrict__ Wo, float* __restrict__ WT) {
  __shared__ float tl[32][33];
  int bx = blockIdx.x & 3, by = blockIdx.x >> 2;
  int t = threadIdx.x;
  int tx = t & 31, ty = t >> 5;
  #pragma unroll
  for (int i = 0; i < 4; ++i)
    tl[ty + i * 8][tx] = Wo[(size_t)(by * 32 + ty + i * 8) * 128 + bx * 32 + tx];
  __syncthreads();
  #pragma unroll
  for (int i = 0; i < 4; ++i)
    WT[(size_t)(bx * 32 + ty + i * 8) * 128 + by * 32 + tx] = tl[tx][ty + i * 8];
}

// ---------------- merge 4 directions + LayerNorm + out_proj ----------------
__global__ __launch_bounds__(256)
void k_merge(const float* __restrict__ ysz, const float* __restrict__ ln_g,
             const float* __restrict__ ln_b, const float* __restrict__ WT,
             float* __restrict__ out) {
  __shared__ __align__(16) float ynT[128][20];
  __shared__ float red[4][8][2];
  int blk = blockIdx.x;          // 512: b = blk>>8, ptile = blk&255
  int b = blk >> 8;
  int p0 = (blk & 255) * 16;
  int tid = threadIdx.x;
  int t = tid & 127;             // channel
  int half = tid >> 7;           // 0/1
  int w = tid >> 6;              // wave 0..3
  float g = ln_g[t], bb = ln_b[t];
  const float* yb = ysz + (size_t)b * 4 * PIX * 128;
  float yv[8];
  #pragma unroll
  for (int i = 0; i < 8; ++i) {
    int p = p0 + 2 * i + half;
    float y = yb[((size_t)0 * PIX + p) * 128 + t]
            + yb[((size_t)1 * PIX + p) * 128 + t]
            + yb[((size_t)2 * PIX + p) * 128 + t]
            + yb[((size_t)3 * PIX + p) * 128 + t];
    yv[i] = y;
    float s1 = y, s2 = y * y;
    #pragma unroll
    for (int off = 32; off; off >>= 1) {
      s1 += __shfl_xor(s1, off);
      s2 += __shfl_xor(s2, off);
    }
    if ((tid & 63) == 0) { red[w][i][0] = s1; red[w][i][1] = s2; }
  }
  __syncthreads();
  #pragma unroll
  for (int i = 0; i < 8; ++i) {
    int pl = 2 * i + half;
    float S1 = red[half * 2][i][0] + red[half * 2 + 1][i][0];
    float S2 = red[half * 2][i][1] + red[half * 2 + 1][i][1];
    float mu = S1 * (1.0f / 128.0f);
    float var = S2 * (1.0f / 128.0f) - mu * mu;
    float rs = rsqrtf(var + 1e-5f);
    ynT[t][pl] = (yv[i] - mu) * rs * g + bb;
  }
  __syncthreads();
  float acc[8];
  #pragma unroll
  for (int i = 0; i < 8; ++i) acc[i] = 0.0f;
  for (int dd = 0; dd < 128; ++dd) {
    float wv = WT[(size_t)dd * 128 + t];
    const float4* yr = (const float4*)(&ynT[dd][half * 8]);
    float4 ya = yr[0], yb4 = yr[1];
    acc[0] = fmaf(ya.x,  wv, acc[0]);
    acc[1] = fmaf(ya.y,  wv, acc[1]);
    acc[2] = fmaf(ya.z,  wv, acc[2]);
    acc[3] = fmaf(ya.w,  wv, acc[3]);
    acc[4] = fmaf(yb4.x, wv, acc[4]);
    acc[5] = fmaf(yb4.y, wv, acc[5]);
    acc[6] = fmaf(yb4.z, wv, acc[6]);
    acc[7] = fmaf(yb4.w, wv, acc[7]);
  }
  float* dst = out + ((size_t)b * 128 + t) * PIX + p0 + half * 8;
  float4 v0 = make_float4(acc[0], acc[1], acc[2], acc[3]);
  float4 v1 = make_float4(acc[4], acc[5], acc[6], acc[7]);
  *(float4*)(dst) = v0;
  *(float4*)(dst + 4) = v1;
}

extern "C" void kernel_launch(void* const* d_in, const int* in_sizes, int n_in,
                              void* d_out, int out_size, void* d_ws, size_t ws_size,
                              hipStream_t stream) {
  const float* x         = (const float*)d_in[0];
  // d_in[1] record_len unused
  const float* nam       = (const float*)d_in[2];
  const float* in_proj_w = (const float*)d_in[3];
  const float* conv_w    = (const float*)d_in[4];
  const float* conv_b    = (const float*)d_in[5];
  const float* x_proj_w  = (const float*)d_in[6];
  const float* dt_w      = (const float*)d_in[7];
  const float* dt_b      = (const float*)d_in[8];
  const float* A_logs    = (const float*)d_in[9];
  const float* Ds        = (const float*)d_in[10];
  const float* ln_g      = (const float*)d_in[11];
  const float* ln_b      = (const float*)d_in[12];
  const float* out_proj_w= (const float*)d_in[13];
  float* out = (float*)d_out;
  float* ws  = (float*)d_ws;

  // workspace layout (floats); total ~31.0M floats (~124 MB)
  float* warped = ws;                          // 5,242,880 (later: h_out 4.2M)
  float* alpha  = warped + 5242880;            //    40,960
  float* X0     = alpha  + 40960;              // 5,242,880 (later: h_in 4.2M)
  float* XT     = X0     + 5242880;            // 5,242,880
  float* ZdtB   = XT     + 5242880;            // 3,932,160
  float* ZC     = ZdtB   + 3932160;            // 2,621,440
  float* sums   = ZC     + 2621440;            //   262,144
  float* ysz    = sums   + 262144;             // 4,194,304
  float* cumdt  = ysz    + 4194304;            // 4,194,304
  float* WT     = cumdt  + 4194304;            //    16,384

  float* h_out = warped;   // warped dead after k_gemm_in
  float* h_in  = X0;       // X0 dead after k_conv

  k_warp   <<<20480, 256, 0, stream>>>(x, nam, warped);
  k_alpha  <<<128,   256, 0, stream>>>(warped, nam, alpha);
  k_gemm_in<<<640,   256, 0, stream>>>(warped, alpha, in_proj_w, X0);
  k_conv   <<<20480, 256, 0, stream>>>(X0, conv_w, conv_b, XT);
  k_gemmZ  <<<640,   256, 0, stream>>>(XT, x_proj_w, ZdtB, ZC);
  k_scan1  <<<1024,  256, 0, stream>>>(XT, ZdtB, ZC, dt_w, dt_b, A_logs, Ds,
                                       h_out, sums, ysz, cumdt);
  k_combine<<<64,    256, 0, stream>>>(A_logs, sums, h_out, h_in);
  k_fixup  <<<16384, 256, 0, stream>>>(ZC, A_logs, h_in, cumdt, ysz);
  k_wt     <<<16,    256, 0, stream>>>(out_proj_w, WT);
  k_merge  <<<512,   256, 0, stream>>>(ysz, ln_g, ln_b, WT, out);
}

// Round 4
// 307.323 us; speedup vs baseline: 2.1734x; 1.2010x over previous
//
#include <hip/hip_runtime.h>
#include <math.h>

#define B_S   2
#define PIX   4096
#define LL    20480
#define NS    16
#define RR    8
#define NCHK  256     // chunks per sequence
#define LC    80      // steps per chunk
#define SUBS  20      // steps per staging sub-chunk
#define NSUB  4       // LC/SUBS
#define NGRP  16      // chunk groups for combine
#define GCH   16      // chunks per group

template<int K>
__device__ __forceinline__ int zmapT(int l) {
  if (K == 0) return l;
  if (K == 1) return ((l % 5) << 12) + l / 5;
  if (K == 2) return 20479 - l;
  int lr = 20479 - l;
  return ((lr % 5) << 12) + lr / 5;
}

// ---------------- affine grid + bilinear grid_sample ----------------
__global__ __launch_bounds__(256)
void k_warp(const float* __restrict__ x, const float* __restrict__ nam,
            float* __restrict__ warped) {
  int g = blockIdx.x * 256 + threadIdx.x;        // B*K*C*PIX = 5,242,880
  int p  = g & 4095;
  int c  = (g >> 12) & 127;
  int bk = g >> 19;                              // 0..9
  int b = bk / 5, k = bk - b * 5;
  const float* th = nam + (size_t)(b * 25 + k) * 6;   // nam[b,0,k]
  float gx = ((p & 63) + 0.5f) * 0.03125f - 1.0f;
  float gy = ((p >> 6) + 0.5f) * 0.03125f - 1.0f;
  float grx = th[0] * gx + th[1] * gy + th[2];
  float gry = th[3] * gx + th[4] * gy + th[5];
  float ix = ((grx + 1.0f) * 64.0f - 1.0f) * 0.5f;
  float iy = ((gry + 1.0f) * 64.0f - 1.0f) * 0.5f;
  float x0 = floorf(ix), y0 = floorf(iy);
  float fx = ix - x0,  fy = iy - y0;
  const float* src = x + (size_t)(bk * 128 + c) * PIX;
  float acc = 0.0f;
  #pragma unroll
  for (int dy = 0; dy < 2; ++dy) {
    float yf = y0 + dy;
    float wy = dy ? fy : 1.0f - fy;
    if (yf < 0.0f || yf > 63.0f) continue;
    int yi = (int)yf;
    #pragma unroll
    for (int dx = 0; dx < 2; ++dx) {
      float xf = x0 + dx;
      float wx = dx ? fx : 1.0f - fx;
      if (xf < 0.0f || xf > 63.0f) continue;
      acc += wx * wy * src[yi * 64 + (int)xf];
    }
  }
  warped[g] = acc;
}

// ---------------- per-pixel similarity -> softmax alpha ----------------
__global__ __launch_bounds__(512)
void k_alpha(const float* __restrict__ warped, const float* __restrict__ nam,
             float* __restrict__ alpha) {
  __shared__ float part[8][64][9];
  int blk = blockIdx.x;            // 128 blocks
  int b = blk >> 6;
  int p0 = (blk & 63) << 6;
  int wv = threadIdx.x >> 6, lane = threadIdx.x & 63;
  int p = p0 + lane;
  const float* wb = warped + (size_t)b * 5 * 128 * PIX + p;
  float dot[5] = {0,0,0,0,0}, ssq[5] = {0,0,0,0,0};
  int c0 = wv * 16;
  for (int c = c0; c < c0 + 16; ++c) {
    float w0 = wb[(size_t)c * PIX];
    ssq[0] += w0 * w0;
    #pragma unroll
    for (int k = 1; k < 5; ++k) {
      float wk = wb[((size_t)k * 128 + c) * PIX];
      dot[k] += w0 * wk;
      ssq[k] += wk * wk;
    }
  }
  part[wv][lane][0] = ssq[0];
  #pragma unroll
  for (int k = 1; k < 5; ++k) {
    part[wv][lane][k] = dot[k];
    part[wv][lane][4 + k] = ssq[k];
  }
  __syncthreads();
  if (threadIdx.x < 64) {
    float q[9];
    #pragma unroll
    for (int j = 0; j < 9; ++j) {
      float s = 0.0f;
      #pragma unroll
      for (int w = 0; w < 8; ++w) s += part[w][lane][j];
      q[j] = s;
    }
    float n0 = fmaxf(sqrtf(q[0]), 1e-6f);
    float logit[5];
    #pragma unroll
    for (int k = 0; k < 5; ++k) {
      float dotk = (k == 0) ? q[0] : q[k];
      float ssqk = (k == 0) ? q[0] : q[4 + k];
      float nk = fmaxf(sqrtf(ssqk), 1e-6f);
      float sim = fminf(fmaxf(dotk / (n0 * nk), -1.0f), 1.0f);
      float r = fmaxf(1.0f - sim, 0.0f);
      float xr = r * (1.0f / 0.3f);
      float tt = fmaxf(1.0f - xr * xr, 0.0f);
      float wp = fmaxf(tt * tt, 1e-6f);
      const float* th = nam + (size_t)(b * 25 + k) * 6;
      float tx = th[2], ty = th[5];
      float yaw = fabsf(atan2f(th[1], th[0]));
      float gk = 1.0f / (1.0f + __expf(-(2.0f - 0.4f * sqrtf(tx*tx + ty*ty) - 0.8f * yaw)));
      logit[k] = __logf(wp + 1e-8f) + __logf(gk + 1e-8f);
    }
    float m = logit[0];
    #pragma unroll
    for (int k = 1; k < 5; ++k) m = fmaxf(m, logit[k]);
    float e[5], s = 0.0f;
    #pragma unroll
    for (int k = 0; k < 5; ++k) { e[k] = __expf(logit[k] - m); s += e[k]; }
    float inv = 1.0f / s;
    #pragma unroll
    for (int k = 0; k < 5; ++k)
      alpha[((size_t)(b * 5 + k)) * PIX + p] = e[k] * inv;
  }
}

// ---- in_proj GEMM fused with tokens transpose: X0 = (warped*alpha)^T @ W^T ----
__global__ __launch_bounds__(256, 4)
void k_gemm_in(const float* __restrict__ warped, const float* __restrict__ alpha,
               const float* __restrict__ W, float* __restrict__ X0) {
  __shared__ float xl[64][129];
  __shared__ __align__(16) float wlT[32][132];
  int t = threadIdx.x;
  int row0 = blockIdx.x * 64;             // 640 blocks, rows = b*LL + a*4096 + p
  int b = row0 / LL;
  int z0 = row0 - b * LL;
  int a = z0 >> 12;
  int p0 = z0 & 4095;
  int ba = b * 5 + a;
  int r = t & 63, cg = t >> 6;
  float av = alpha[(size_t)ba * PIX + p0 + r];
  #pragma unroll
  for (int i = 0; i < 32; ++i) {
    int c = cg * 32 + i;
    xl[r][c] = warped[((size_t)ba * 128 + c) * PIX + p0 + r] * av;
  }
  int zl = t & 63, mg = t >> 6;
  float acc[32];
  #pragma unroll
  for (int i = 0; i < 32; ++i) acc[i] = 0.0f;
  for (int c0 = 0; c0 < 128; c0 += 32) {
    __syncthreads();
    #pragma unroll
    for (int i = 0; i < 16; ++i) {
      int m = (t >> 5) * 16 + i;
      wlT[t & 31][m] = W[(size_t)m * 128 + c0 + (t & 31)];
    }
    __syncthreads();
    for (int cc = 0; cc < 32; ++cc) {
      float xv = xl[zl][c0 + cc];
      const float4* wr = (const float4*)(&wlT[cc][mg * 32]);
      #pragma unroll
      for (int q = 0; q < 8; ++q) {
        float4 w4 = wr[q];
        acc[q*4+0] = fmaf(w4.x, xv, acc[q*4+0]);
        acc[q*4+1] = fmaf(w4.y, xv, acc[q*4+1]);
        acc[q*4+2] = fmaf(w4.z, xv, acc[q*4+2]);
        acc[q*4+3] = fmaf(w4.w, xv, acc[q*4+3]);
      }
    }
  }
  __syncthreads();
  #pragma unroll
  for (int q = 0; q < 32; ++q) xl[zl][mg * 32 + q] = acc[q];
  __syncthreads();
  #pragma unroll
  for (int i = 0; i < 32; ++i) {
    int idx = i * 256 + t;
    X0[((size_t)row0 + (idx >> 7)) * 128 + (idx & 127)] = xl[idx >> 7][idx & 127];
  }
}

// ---------------- depthwise 3x3 conv over (a=5, p=4096) + SiLU ----------------
__global__ __launch_bounds__(256)
void k_conv(const float* __restrict__ X0, const float* __restrict__ cw,
            const float* __restrict__ cb, float* __restrict__ XT) {
  int g = blockIdx.x * 256 + threadIdx.x;   // B*LL*128 = 5,242,880
  int d = g & 127;
  int zz = g >> 7;           // b*LL + z
  int b = zz / LL, z = zz - b * LL;
  int a = z >> 12, p = z & 4095;
  float acc = cb[d];
  #pragma unroll
  for (int di = 0; di < 3; ++di) {
    int aa = a + di - 1;
    if (aa < 0 || aa >= 5) continue;
    #pragma unroll
    for (int dj = 0; dj < 3; ++dj) {
      int pp = p + dj - 1;
      if (pp < 0 || pp >= PIX) continue;
      acc += cw[d * 9 + di * 3 + dj] * X0[((size_t)b * LL + aa * PIX + pp) * 128 + d];
    }
  }
  float sg = 1.0f / (1.0f + __expf(-acc));
  XT[g] = acc * sg;
}

// ---- x_proj GEMM, output permuted to scan order, split ZdtB[24] / ZC[16] ----
__global__ __launch_bounds__(256, 4)
void k_gemmZ(const float* __restrict__ X, const float* __restrict__ W,
             float* __restrict__ ZdtB, float* __restrict__ ZC) {
  __shared__ float xl[64][129];
  __shared__ __align__(16) float wlT[32][164];
  int t = threadIdx.x;
  int row0 = blockIdx.x * 64;
  #pragma unroll
  for (int i = 0; i < 32; ++i) {
    int idx = i * 256 + t;
    xl[idx >> 7][idx & 127] = X[((size_t)row0 + (idx >> 7)) * 128 + (idx & 127)];
  }
  int zl = t & 63, mg = t >> 6;
  float acc[40];
  #pragma unroll
  for (int i = 0; i < 40; ++i) acc[i] = 0.0f;
  for (int c0 = 0; c0 < 128; c0 += 32) {
    __syncthreads();
    #pragma unroll
    for (int i = 0; i < 20; ++i) {
      int m = (t >> 5) * 20 + i;
      wlT[t & 31][m] = W[(size_t)m * 128 + c0 + (t & 31)];
    }
    __syncthreads();
    for (int cc = 0; cc < 32; ++cc) {
      float xv = xl[zl][c0 + cc];
      const float4* wr = (const float4*)(&wlT[cc][mg * 40]);
      #pragma unroll
      for (int q = 0; q < 10; ++q) {
        float4 w4 = wr[q];
        acc[q*4+0] = fmaf(w4.x, xv, acc[q*4+0]);
        acc[q*4+1] = fmaf(w4.y, xv, acc[q*4+1]);
        acc[q*4+2] = fmaf(w4.z, xv, acc[q*4+2]);
        acc[q*4+3] = fmaf(w4.w, xv, acc[q*4+3]);
      }
    }
  }
  int row = row0 + zl;
  int b = row / LL, z = row - b * LL;
  int a = z >> 12, qq = z & 4095;
  int l;
  if (mg == 0)      l = z;
  else if (mg == 1) l = 5 * qq + a;
  else if (mg == 2) l = 20479 - z;
  else              l = 20479 - (5 * qq + a);
  float* dD = ZdtB + ((size_t)(b * 4 + mg) * LL + l) * 24;
  #pragma unroll
  for (int q2 = 0; q2 < 6; ++q2) {
    float4 v = make_float4(acc[q2*4], acc[q2*4+1], acc[q2*4+2], acc[q2*4+3]);
    *(float4*)(dD + q2 * 4) = v;
  }
  float* dC = ZC + ((size_t)(b * 4 + mg) * LL + l) * 16;
  #pragma unroll
  for (int q2 = 0; q2 < 4; ++q2) {
    float4 v = make_float4(acc[24+q2*4], acc[24+q2*4+1], acc[24+q2*4+2], acc[24+q2*4+3]);
    *(float4*)(dC + q2 * 4) = v;
  }
}

// ------- single-pass chunked selective scan (per-wave, barrier-free) -------
template<int K>
__device__ void scan_body(int b, int chunk, int dh, int lane,
    const float* __restrict__ XT, const float* __restrict__ ZdtB,
    const float* __restrict__ ZC,
    const float* __restrict__ dt_w, const float* __restrict__ dt_b,
    const float* __restrict__ A_logs, const float* __restrict__ Ds,
    float* __restrict__ h_out, float* __restrict__ sumdts,
    float* __restrict__ ysz, float* __restrict__ cumdtv,
    float* stD, float* stC, float* xs)
{
  const int d = dh * 64 + lane;
  const int kd = K * 128 + d;
  bool chainok = true;
  #pragma unroll
  for (int n = 0; n < NS; ++n) {
    float An = -__expf(A_logs[(size_t)kd * 16 + n]);
    chainok = chainok && (fabsf(An + (float)(n + 1)) < 3e-5f * (float)(n + 1));
  }
  float dw[RR];
  #pragma unroll
  for (int r = 0; r < RR; ++r) dw[r] = dt_w[(size_t)kd * 8 + r];
  const float dtb = dt_b[kd], dsv = Ds[kd];
  float h[NS];
  #pragma unroll
  for (int n = 0; n < NS; ++n) h[n] = 0.0f;
  float sdt = 0.0f;
  const int seq = b * 4 + K;
  const float* ZDs = ZdtB + (size_t)seq * LL * 24;
  const float* ZCs = ZC + (size_t)seq * LL * 16;
  const float* Xb = XT + (size_t)b * LL * 128;
  float* ysb = ysz + (size_t)seq * PIX * 128;
  float* cdb = cumdtv + (size_t)seq * PIX * 128;
  const int l0 = chunk * LC;

  if (__all(chainok ? 1 : 0)) {
    #pragma unroll 1
    for (int sub = 0; sub < NSUB; ++sub) {
      const int ls = l0 + sub * SUBS;
      // stage dt/B rows (480 floats) via per-wave LDS (wave-synchronous)
      #pragma unroll
      for (int i = 0; i < 8; ++i) {
        int idx = i * 64 + lane;
        if (idx < SUBS * 24) stD[idx] = ZDs[(size_t)ls * 24 + idx];
      }
      int s0c = 0;
      bool needC;
      if (K == 0)      needC = (ls < PIX);
      else if (K == 2) needC = (ls + SUBS > LL - PIX);
      else             needC = true;
      if (K == 1) s0c = (5 - (ls % 5)) % 5;
      if (K == 3) s0c = (9 - (ls % 5)) % 5;
      if (needC) {
        if (K == 0 || K == 2) {
          #pragma unroll
          for (int i = 0; i < 5; ++i) {
            int idx = i * 64 + lane;
            stC[idx] = ZCs[(size_t)ls * 16 + idx];
          }
        } else {
          int j = lane >> 4, col = lane & 15;
          int l = ls + s0c + 5 * j;
          stC[lane] = ZCs[(size_t)l * 16 + col];
        }
      }
      // LDS-stage x for 20 steps (per-wave slab, no barriers, no VGPR cost)
      #pragma unroll
      for (int s = 0; s < SUBS; ++s) {
        int z = zmapT<K>(ls + s);
        xs[s * 64 + lane] = Xb[(size_t)z * 128 + d];
      }
      int zc = 0;
      if (K == 1) zc = (ls + s0c) / 5;
      if (K == 3) zc = (20479 - ls - s0c) / 5;
      int yj = 0;
      #pragma unroll
      for (int s = 0; s < SUBS; ++s) {
        const float4* rD = (const float4*)(stD + s * 24);
        float4 ra = rD[0], rb4 = rD[1];
        float dtl = dtb;
        dtl = fmaf(dw[0], ra.x, dtl);  dtl = fmaf(dw[1], ra.y, dtl);
        dtl = fmaf(dw[2], ra.z, dtl);  dtl = fmaf(dw[3], ra.w, dtl);
        dtl = fmaf(dw[4], rb4.x, dtl); dtl = fmaf(dw[5], rb4.y, dtl);
        dtl = fmaf(dw[6], rb4.z, dtl); dtl = fmaf(dw[7], rb4.w, dtl);
        float edt = __expf(dtl);
        float e1 = __builtin_amdgcn_rcpf(1.0f + edt);  // exp(-softplus(dtl))
        float dt = (dtl > 20.0f) ? dtl : __logf(1.0f + edt);
        sdt += dt;
        float dtx = dt * xs[s * 64 + lane];
        float4 b0 = rD[2], b1 = rD[3], b2 = rD[4], b3 = rD[5];
        float e2 = e1*e1, e4 = e2*e2, e8 = e4*e4;
        float p3 = e2*e1, p5 = e4*e1, p6 = e4*e2, p7 = e4*p3;
        h[0]  = fmaf(h[0],  e1,    dtx*b0.x);
        h[1]  = fmaf(h[1],  e2,    dtx*b0.y);
        h[2]  = fmaf(h[2],  p3,    dtx*b0.z);
        h[3]  = fmaf(h[3],  e4,    dtx*b0.w);
        h[4]  = fmaf(h[4],  p5,    dtx*b1.x);
        h[5]  = fmaf(h[5],  p6,    dtx*b1.y);
        h[6]  = fmaf(h[6],  p7,    dtx*b1.z);
        h[7]  = fmaf(h[7],  e8,    dtx*b1.w);
        h[8]  = fmaf(h[8],  e8*e1, dtx*b2.x);
        h[9]  = fmaf(h[9],  e8*e2, dtx*b2.y);
        h[10] = fmaf(h[10], e8*p3, dtx*b2.z);
        h[11] = fmaf(h[11], e8*e4, dtx*b2.w);
        h[12] = fmaf(h[12], e8*p5, dtx*b3.x);
        h[13] = fmaf(h[13], e8*p6, dtx*b3.y);
        h[14] = fmaf(h[14], e8*p7, dtx*b3.z);
        h[15] = fmaf(h[15], e8*e8, dtx*b3.w);
        bool doY;
        int z;
        if (K == 0)      { z = ls + s;            doY = (z < PIX); }
        else if (K == 2) { z = 20479 - (ls + s);  doY = (z < PIX); }
        else             { z = zc;                doY = ((s % 5) == s0c); }
        if (doY) {
          const float4* rC = (const float4*)(stC + ((K == 0 || K == 2) ? s : yj) * 16);
          float4 c0 = rC[0], c1 = rC[1], c2 = rC[2], c3 = rC[3];
          float y = dsv * xs[s * 64 + lane];
          y = fmaf(h[0],  c0.x, y); y = fmaf(h[1],  c0.y, y);
          y = fmaf(h[2],  c0.z, y); y = fmaf(h[3],  c0.w, y);
          y = fmaf(h[4],  c1.x, y); y = fmaf(h[5],  c1.y, y);
          y = fmaf(h[6],  c1.z, y); y = fmaf(h[7],  c1.w, y);
          y = fmaf(h[8],  c2.x, y); y = fmaf(h[9],  c2.y, y);
          y = fmaf(h[10], c2.z, y); y = fmaf(h[11], c2.w, y);
          y = fmaf(h[12], c3.x, y); y = fmaf(h[13], c3.y, y);
          y = fmaf(h[14], c3.z, y); y = fmaf(h[15], c3.w, y);
          size_t o = (size_t)z * 128 + d;
          ysb[o] = y;
          cdb[o] = sdt;
          ++yj;
          if (K == 1) ++zc;
          if (K == 3) --zc;
        }
      }
    }
  } else {
    // general fallback (compact, rarely taken)
    float An[NS];
    #pragma unroll
    for (int n = 0; n < NS; ++n) An[n] = -__expf(A_logs[(size_t)kd * 16 + n]);
    #pragma unroll 1
    for (int l = l0; l < l0 + LC; ++l) {
      int z = zmapT<K>(l);
      const float* rowD = ZDs + (size_t)l * 24;
      float dtl = dtb;
      #pragma unroll
      for (int r = 0; r < RR; ++r) dtl += dw[r] * rowD[r];
      float edt = __expf(dtl);
      float dt = (dtl > 20.0f) ? dtl : __logf(1.0f + edt);
      sdt += dt;
      float xv = Xb[(size_t)z * 128 + d];
      float dtx = dt * xv;
      #pragma unroll
      for (int n = 0; n < NS; ++n)
        h[n] = h[n] * __expf(dt * An[n]) + dtx * rowD[8 + n];
      if (z < PIX) {
        const float* rowC = ZCs + (size_t)l * 16;
        float y = dsv * xv;
        #pragma unroll
        for (int n = 0; n < NS; ++n) y = fmaf(h[n], rowC[n], y);
        size_t o = (size_t)z * 128 + d;
        ysb[o] = y;
        cdb[o] = sdt;
      }
    }
  }
  float* ho = h_out + (((size_t)seq * NCHK + chunk) * 128 + d) * 16;
  #pragma unroll
  for (int n = 0; n < NS; ++n) ho[n] = h[n];
  sumdts[((size_t)seq * NCHK + chunk) * 128 + d] = sdt;
}

__global__ __launch_bounds__(256, 2)
void k_scan1(const float* __restrict__ XT, const float* __restrict__ ZdtB,
             const float* __restrict__ ZC,
             const float* __restrict__ dt_w, const float* __restrict__ dt_b,
             const float* __restrict__ A_logs, const float* __restrict__ Ds,
             float* __restrict__ h_out, float* __restrict__ sumdts,
             float* __restrict__ ysz, float* __restrict__ cumdtv) {
  __shared__ __align__(16) float stD_all[4][SUBS * 24];
  __shared__ __align__(16) float stC_all[4][SUBS * 16];
  __shared__ __align__(16) float xs_all[4][SUBS * 64];
  int tid = threadIdx.x, wid = tid >> 6, lane = tid & 63;
  int bid = blockIdx.x;            // 1024 = B*4*(NCHK/2)
  int cp = bid & 127;
  int k = (bid >> 7) & 3;
  int b = bid >> 9;
  int chunk = cp * 2 + (wid >> 1);
  int dh = wid & 1;
  float* stD = stD_all[wid];
  float* stC = stC_all[wid];
  float* xs  = xs_all[wid];
  switch (k) {
    case 0: scan_body<0>(b, chunk, dh, lane, XT, ZdtB, ZC, dt_w, dt_b, A_logs, Ds, h_out, sumdts, ysz, cumdtv, stD, stC, xs); break;
    case 1: scan_body<1>(b, chunk, dh, lane, XT, ZdtB, ZC, dt_w, dt_b, A_logs, Ds, h_out, sumdts, ysz, cumdtv, stD, stC, xs); break;
    case 2: scan_body<2>(b, chunk, dh, lane, XT, ZdtB, ZC, dt_w, dt_b, A_logs, Ds, h_out, sumdts, ysz, cumdtv, stD, stC, xs); break;
    default: scan_body<3>(b, chunk, dh, lane, XT, ZdtB, ZC, dt_w, dt_b, A_logs, Ds, h_out, sumdts, ysz, cumdtv, stD, stC, xs); break;
  }
}

// ---- combine level A: per-group affine fold (Ag = prod a, Bg = fold b) ----
__global__ __launch_bounds__(256)
void k_comb_a(const float* __restrict__ A_logs, const float* __restrict__ sumdts,
              const float* __restrict__ h_out, float* __restrict__ Ag,
              float* __restrict__ Bg) {
  int g = blockIdx.x * 256 + threadIdx.x;   // 8*16*128*16 = 262144
  int n = g & 15;
  int d = (g >> 4) & 127;
  int grp = (g >> 11) & 15;
  int seq = g >> 15;
  int k = seq & 3;
  float An = -__expf(A_logs[(size_t)(k * 128 + d) * 16 + n]);
  float A = 1.0f, Bv = 0.0f;
  size_t cbase = (size_t)seq * NCHK + grp * GCH;
  #pragma unroll 4
  for (int j = 0; j < GCH; ++j) {
    float a = __expf(An * sumdts[(cbase + j) * 128 + d]);
    float b = h_out[((cbase + j) * 128 + d) * 16 + n];
    A *= a;
    Bv = Bv * a + b;
  }
  size_t o = (((size_t)seq * NGRP + grp) * 128 + d) * 16 + n;
  Ag[o] = A;
  Bg[o] = Bv;
}

// ---- combine level B: prefix over 16 groups ----
__global__ __launch_bounds__(256)
void k_comb_b(const float* __restrict__ Ag, const float* __restrict__ Bg,
              float* __restrict__ Hg) {
  int g = blockIdx.x * 256 + threadIdx.x;   // 8*128*16 = 16384
  int n = g & 15;
  int d = (g >> 4) & 127;
  int seq = g >> 11;
  float H = 0.0f;
  #pragma unroll
  for (int grp = 0; grp < NGRP; ++grp) {
    size_t o = (((size_t)seq * NGRP + grp) * 128 + d) * 16 + n;
    Hg[o] = H;
    H = Ag[o] * H + Bg[o];
  }
}

// ---- combine level C: replay within group -> h_in per chunk ----
__global__ __launch_bounds__(256)
void k_comb_c(const float* __restrict__ A_logs, const float* __restrict__ sumdts,
              const float* __restrict__ h_out, const float* __restrict__ Hg,
              float* __restrict__ h_in) {
  int g = blockIdx.x * 256 + threadIdx.x;   // 262144
  int n = g & 15;
  int d = (g >> 4) & 127;
  int grp = (g >> 11) & 15;
  int seq = g >> 15;
  int k = seq & 3;
  float An = -__expf(A_logs[(size_t)(k * 128 + d) * 16 + n]);
  float h = Hg[(((size_t)seq * NGRP + grp) * 128 + d) * 16 + n];
  size_t cbase = (size_t)seq * NCHK + grp * GCH;
  #pragma unroll 4
  for (int j = 0; j < GCH; ++j) {
    size_t o = ((cbase + j) * 128 + d) * 16 + n;
    h_in[o] = h;
    float a = __expf(An * sumdts[(cbase + j) * 128 + d]);
    h = a * h + h_out[o];
  }
}

// ------------- add cross-chunk correction: y += C · (E(l)·h_in) -------------
__global__ __launch_bounds__(256)
void k_fixup(const float* __restrict__ ZC, const float* __restrict__ A_logs,
             const float* __restrict__ h_in, const float* __restrict__ cumdtv,
             float* __restrict__ ysz) {
  int g = blockIdx.x * 256 + threadIdx.x;   // B*4*PIX*128 = 4,194,304
  int d = g & 127;
  int z = (g >> 7) & 4095;
  int k = (g >> 19) & 3;
  int b = g >> 21;
  int l;
  if (k == 0)      l = z;
  else if (k == 1) l = 5 * z;
  else if (k == 2) l = 20479 - z;
  else             l = 20479 - 5 * z;
  int chunk = l / LC;
  int kd = k * 128 + d;
  float cd = cumdtv[g];
  const float* hi = h_in + (((size_t)(b * 4 + k) * NCHK + chunk) * 128 + d) * 16;
  const float* Crow = ZC + ((size_t)(b * 4 + k) * LL + l) * 16;
  float acc = 0.0f;
  #pragma unroll
  for (int n = 0; n < NS; ++n) {
    float An = -__expf(A_logs[(size_t)kd * 16 + n]);
    acc += Crow[n] * hi[n] * __expf(An * cd);
  }
  ysz[g] += acc;
}

// ---------------- transpose out_proj_w ----------------
__global__ __launch_bounds__(256)
void k_wt(const float* __restrict__ Wo, float* __restrict__ WT) {
  __shared__ float tl[32][33];
  int bx = blockIdx.x & 3, by = blockIdx.x >> 2;
  int t = threadIdx.x;
  int tx = t & 31, ty = t >> 5;
  #pragma unroll
  for (int i = 0; i < 4; ++i)
    tl[ty + i * 8][tx] = Wo[(size_t)(by * 32 + ty + i * 8) * 128 + bx * 32 + tx];
  __syncthreads();
  #pragma unroll
  for (int i = 0; i < 4; ++i)
    WT[(size_t)(bx * 32 + ty + i * 8) * 128 + by * 32 + tx] = tl[tx][ty + i * 8];
}

// ---------------- merge 4 directions + LayerNorm + out_proj ----------------
__global__ __launch_bounds__(256)
void k_merge(const float* __restrict__ ysz, const float* __restrict__ ln_g,
             const float* __restrict__ ln_b, const float* __restrict__ WT,
             float* __restrict__ out) {
  __shared__ __align__(16) float ynT[128][20];
  __shared__ float red[4][8][2];
  int blk = blockIdx.x;          // 512: b = blk>>8, ptile = blk&255
  int b = blk >> 8;
  int p0 = (blk & 255) * 16;
  int tid = threadIdx.x;
  int t = tid & 127;             // channel
  int half = tid >> 7;           // 0/1
  int w = tid >> 6;              // wave 0..3
  float g = ln_g[t], bb = ln_b[t];
  const float* yb = ysz + (size_t)b * 4 * PIX * 128;
  float yv[8];
  #pragma unroll
  for (int i = 0; i < 8; ++i) {
    int p = p0 + 2 * i + half;
    float y = yb[((size_t)0 * PIX + p) * 128 + t]
            + yb[((size_t)1 * PIX + p) * 128 + t]
            + yb[((size_t)2 * PIX + p) * 128 + t]
            + yb[((size_t)3 * PIX + p) * 128 + t];
    yv[i] = y;
    float s1 = y, s2 = y * y;
    #pragma unroll
    for (int off = 32; off; off >>= 1) {
      s1 += __shfl_xor(s1, off);
      s2 += __shfl_xor(s2, off);
    }
    if ((tid & 63) == 0) { red[w][i][0] = s1; red[w][i][1] = s2; }
  }
  __syncthreads();
  #pragma unroll
  for (int i = 0; i < 8; ++i) {
    int pl = 2 * i + half;
    float S1 = red[half * 2][i][0] + red[half * 2 + 1][i][0];
    float S2 = red[half * 2][i][1] + red[half * 2 + 1][i][1];
    float mu = S1 * (1.0f / 128.0f);
    float var = S2 * (1.0f / 128.0f) - mu * mu;
    float rs = rsqrtf(var + 1e-5f);
    ynT[t][pl] = (yv[i] - mu) * rs * g + bb;
  }
  __syncthreads();
  float acc[8];
  #pragma unroll
  for (int i = 0; i < 8; ++i) acc[i] = 0.0f;
  for (int dd = 0; dd < 128; ++dd) {
    float wv = WT[(size_t)dd * 128 + t];
    const float4* yr = (const float4*)(&ynT[dd][half * 8]);
    float4 ya = yr[0], yb4 = yr[1];
    acc[0] = fmaf(ya.x,  wv, acc[0]);
    acc[1] = fmaf(ya.y,  wv, acc[1]);
    acc[2] = fmaf(ya.z,  wv, acc[2]);
    acc[3] = fmaf(ya.w,  wv, acc[3]);
    acc[4] = fmaf(yb4.x, wv, acc[4]);
    acc[5] = fmaf(yb4.y, wv, acc[5]);
    acc[6] = fmaf(yb4.z, wv, acc[6]);
    acc[7] = fmaf(yb4.w, wv, acc[7]);
  }
  float* dst = out + ((size_t)b * 128 + t) * PIX + p0 + half * 8;
  float4 v0 = make_float4(acc[0], acc[1], acc[2], acc[3]);
  float4 v1 = make_float4(acc[4], acc[5], acc[6], acc[7]);
  *(float4*)(dst) = v0;
  *(float4*)(dst + 4) = v1;
}

extern "C" void kernel_launch(void* const* d_in, const int* in_sizes, int n_in,
                              void* d_out, int out_size, void* d_ws, size_t ws_size,
                              hipStream_t stream) {
  const float* x         = (const float*)d_in[0];
  // d_in[1] record_len unused
  const float* nam       = (const float*)d_in[2];
  const float* in_proj_w = (const float*)d_in[3];
  const float* conv_w    = (const float*)d_in[4];
  const float* conv_b    = (const float*)d_in[5];
  const float* x_proj_w  = (const float*)d_in[6];
  const float* dt_w      = (const float*)d_in[7];
  const float* dt_b      = (const float*)d_in[8];
  const float* A_logs    = (const float*)d_in[9];
  const float* Ds        = (const float*)d_in[10];
  const float* ln_g      = (const float*)d_in[11];
  const float* ln_b      = (const float*)d_in[12];
  const float* out_proj_w= (const float*)d_in[13];
  float* out = (float*)d_out;
  float* ws  = (float*)d_ws;

  // workspace layout (floats); total ~31.8M floats (~127 MB)
  float* warped = ws;                          // 5,242,880 (later: h_out 4.2M)
  float* alpha  = warped + 5242880;            //    40,960
  float* X0     = alpha  + 40960;              // 5,242,880 (later: h_in 4.2M)
  float* XT     = X0     + 5242880;            // 5,242,880
  float* ZdtB   = XT     + 5242880;            // 3,932,160
  float* ZC     = ZdtB   + 3932160;            // 2,621,440
  float* sums   = ZC     + 2621440;            //   262,144
  float* ysz    = sums   + 262144;             // 4,194,304
  float* cumdt  = ysz    + 4194304;            // 4,194,304
  float* WT     = cumdt  + 4194304;            //    16,384
  float* Ag     = WT     + 16384;              //   262,144
  float* Bg     = Ag     + 262144;             //   262,144
  float* Hg     = Bg     + 262144;             //   262,144

  float* h_out = warped;   // warped dead after k_gemm_in
  float* h_in  = X0;       // X0 dead after k_conv

  k_warp   <<<20480, 256, 0, stream>>>(x, nam, warped);
  k_alpha  <<<128,   512, 0, stream>>>(warped, nam, alpha);
  k_gemm_in<<<640,   256, 0, stream>>>(warped, alpha, in_proj_w, X0);
  k_conv   <<<20480, 256, 0, stream>>>(X0, conv_w, conv_b, XT);
  k_gemmZ  <<<640,   256, 0, stream>>>(XT, x_proj_w, ZdtB, ZC);
  k_scan1  <<<1024,  256, 0, stream>>>(XT, ZdtB, ZC, dt_w, dt_b, A_logs, Ds,
                                       h_out, sums, ysz, cumdt);
  k_comb_a <<<1024,  256, 0, stream>>>(A_logs, sums, h_out, Ag, Bg);
  k_comb_b <<<64,    256, 0, stream>>>(Ag, Bg, Hg);
  k_comb_c <<<1024,  256, 0, stream>>>(A_logs, sums, h_out, Hg, h_in);
  k_fixup  <<<16384, 256, 0, stream>>>(ZC, A_logs, h_in, cumdt, ysz);
  k_wt     <<<16,    256, 0, stream>>>(out_proj_w, WT);
  k_merge  <<<512,   256, 0, stream>>>(ysz, ln_g, ln_b, WT, out);
}

// Round 5
// 285.989 us; speedup vs baseline: 2.3356x; 1.0746x over previous
//
#include <hip/hip_runtime.h>
#include <math.h>

#define B_S   2
#define PIX   4096
#define LL    20480
#define NS    16
#define RR    8
#define NCHK  256     // chunks per sequence
#define LC    80      // steps per chunk
#define SUBS  16      // steps per staging sub-chunk
#define NSUB  5       // LC/SUBS
#define NGRP  16      // chunk groups for combine
#define GCH   16      // chunks per group
#define K0CP  26      // chunk-pairs kept for K=0 (chunks 0..51 cover l<4160)

typedef float v2f __attribute__((ext_vector_type(2)));

__device__ __forceinline__ v2f pk_mul(v2f a, v2f b) {
  v2f d;
  asm("v_pk_mul_f32 %0, %1, %2" : "=v"(d) : "v"(a), "v"(b));
  return d;
}
// a = b*c + a
#define PK_FMA_ACC(a, b, c) asm("v_pk_fma_f32 %0, %1, %2, %0" : "+v"(a) : "v"(b), "v"(c))
// h = h*e + m
#define PK_DECAY(h, e, m) asm("v_pk_fma_f32 %0, %0, %1, %2" : "+v"(h) : "v"(e), "v"(m))

template<int K>
__device__ __forceinline__ int zmapT(int l) {
  if (K == 0) return l;
  if (K == 1) return ((l % 5) << 12) + l / 5;
  if (K == 2) return 20479 - l;
  int lr = 20479 - l;
  return ((lr % 5) << 12) + lr / 5;
}

// ---------------- affine grid + bilinear grid_sample ----------------
__global__ __launch_bounds__(256)
void k_warp(const float* __restrict__ x, const float* __restrict__ nam,
            float* __restrict__ warped) {
  int g = blockIdx.x * 256 + threadIdx.x;        // B*K*C*PIX = 5,242,880
  int p  = g & 4095;
  int c  = (g >> 12) & 127;
  int bk = g >> 19;                              // 0..9
  int b = bk / 5, k = bk - b * 5;
  const float* th = nam + (size_t)(b * 25 + k) * 6;   // nam[b,0,k]
  float gx = ((p & 63) + 0.5f) * 0.03125f - 1.0f;
  float gy = ((p >> 6) + 0.5f) * 0.03125f - 1.0f;
  float grx = th[0] * gx + th[1] * gy + th[2];
  float gry = th[3] * gx + th[4] * gy + th[5];
  float ix = ((grx + 1.0f) * 64.0f - 1.0f) * 0.5f;
  float iy = ((gry + 1.0f) * 64.0f - 1.0f) * 0.5f;
  float x0 = floorf(ix), y0 = floorf(iy);
  float fx = ix - x0,  fy = iy - y0;
  const float* src = x + (size_t)(bk * 128 + c) * PIX;
  float acc = 0.0f;
  #pragma unroll
  for (int dy = 0; dy < 2; ++dy) {
    float yf = y0 + dy;
    float wy = dy ? fy : 1.0f - fy;
    if (yf < 0.0f || yf > 63.0f) continue;
    int yi = (int)yf;
    #pragma unroll
    for (int dx = 0; dx < 2; ++dx) {
      float xf = x0 + dx;
      float wx = dx ? fx : 1.0f - fx;
      if (xf < 0.0f || xf > 63.0f) continue;
      acc += wx * wy * src[yi * 64 + (int)xf];
    }
  }
  warped[g] = acc;
}

// ---------------- per-pixel similarity -> softmax alpha ----------------
__global__ __launch_bounds__(512)
void k_alpha(const float* __restrict__ warped, const float* __restrict__ nam,
             float* __restrict__ alpha) {
  __shared__ float part[8][64][9];
  int blk = blockIdx.x;            // 128 blocks
  int b = blk >> 6;
  int p0 = (blk & 63) << 6;
  int wv = threadIdx.x >> 6, lane = threadIdx.x & 63;
  int p = p0 + lane;
  const float* wb = warped + (size_t)b * 5 * 128 * PIX + p;
  float dot[5] = {0,0,0,0,0}, ssq[5] = {0,0,0,0,0};
  int c0 = wv * 16;
  for (int c = c0; c < c0 + 16; ++c) {
    float w0 = wb[(size_t)c * PIX];
    ssq[0] += w0 * w0;
    #pragma unroll
    for (int k = 1; k < 5; ++k) {
      float wk = wb[((size_t)k * 128 + c) * PIX];
      dot[k] += w0 * wk;
      ssq[k] += wk * wk;
    }
  }
  part[wv][lane][0] = ssq[0];
  #pragma unroll
  for (int k = 1; k < 5; ++k) {
    part[wv][lane][k] = dot[k];
    part[wv][lane][4 + k] = ssq[k];
  }
  __syncthreads();
  if (threadIdx.x < 64) {
    float q[9];
    #pragma unroll
    for (int j = 0; j < 9; ++j) {
      float s = 0.0f;
      #pragma unroll
      for (int w = 0; w < 8; ++w) s += part[w][lane][j];
      q[j] = s;
    }
    float n0 = fmaxf(sqrtf(q[0]), 1e-6f);
    float logit[5];
    #pragma unroll
    for (int k = 0; k < 5; ++k) {
      float dotk = (k == 0) ? q[0] : q[k];
      float ssqk = (k == 0) ? q[0] : q[4 + k];
      float nk = fmaxf(sqrtf(ssqk), 1e-6f);
      float sim = fminf(fmaxf(dotk / (n0 * nk), -1.0f), 1.0f);
      float r = fmaxf(1.0f - sim, 0.0f);
      float xr = r * (1.0f / 0.3f);
      float tt = fmaxf(1.0f - xr * xr, 0.0f);
      float wp = fmaxf(tt * tt, 1e-6f);
      const float* th = nam + (size_t)(b * 25 + k) * 6;
      float tx = th[2], ty = th[5];
      float yaw = fabsf(atan2f(th[1], th[0]));
      float gk = 1.0f / (1.0f + __expf(-(2.0f - 0.4f * sqrtf(tx*tx + ty*ty) - 0.8f * yaw)));
      logit[k] = __logf(wp + 1e-8f) + __logf(gk + 1e-8f);
    }
    float m = logit[0];
    #pragma unroll
    for (int k = 1; k < 5; ++k) m = fmaxf(m, logit[k]);
    float e[5], s = 0.0f;
    #pragma unroll
    for (int k = 0; k < 5; ++k) { e[k] = __expf(logit[k] - m); s += e[k]; }
    float inv = 1.0f / s;
    #pragma unroll
    for (int k = 0; k < 5; ++k)
      alpha[((size_t)(b * 5 + k)) * PIX + p] = e[k] * inv;
  }
}

// ---- in_proj GEMM fused with tokens transpose: X0 = (warped*alpha)^T @ W^T ----
__global__ __launch_bounds__(256, 4)
void k_gemm_in(const float* __restrict__ warped, const float* __restrict__ alpha,
               const float* __restrict__ W, float* __restrict__ X0) {
  __shared__ float xl[64][129];
  __shared__ __align__(16) float wlT[32][132];
  int t = threadIdx.x;
  int row0 = blockIdx.x * 64;             // 640 blocks, rows = b*LL + a*4096 + p
  int b = row0 / LL;
  int z0 = row0 - b * LL;
  int a = z0 >> 12;
  int p0 = z0 & 4095;
  int ba = b * 5 + a;
  int r = t & 63, cg = t >> 6;
  float av = alpha[(size_t)ba * PIX + p0 + r];
  #pragma unroll
  for (int i = 0; i < 32; ++i) {
    int c = cg * 32 + i;
    xl[r][c] = warped[((size_t)ba * 128 + c) * PIX + p0 + r] * av;
  }
  int zl = t & 63, mg = t >> 6;
  float acc[32];
  #pragma unroll
  for (int i = 0; i < 32; ++i) acc[i] = 0.0f;
  for (int c0 = 0; c0 < 128; c0 += 32) {
    __syncthreads();
    #pragma unroll
    for (int i = 0; i < 16; ++i) {
      int m = (t >> 5) * 16 + i;
      wlT[t & 31][m] = W[(size_t)m * 128 + c0 + (t & 31)];
    }
    __syncthreads();
    for (int cc = 0; cc < 32; ++cc) {
      float xv = xl[zl][c0 + cc];
      const float4* wr = (const float4*)(&wlT[cc][mg * 32]);
      #pragma unroll
      for (int q = 0; q < 8; ++q) {
        float4 w4 = wr[q];
        acc[q*4+0] = fmaf(w4.x, xv, acc[q*4+0]);
        acc[q*4+1] = fmaf(w4.y, xv, acc[q*4+1]);
        acc[q*4+2] = fmaf(w4.z, xv, acc[q*4+2]);
        acc[q*4+3] = fmaf(w4.w, xv, acc[q*4+3]);
      }
    }
  }
  __syncthreads();
  #pragma unroll
  for (int q = 0; q < 32; ++q) xl[zl][mg * 32 + q] = acc[q];
  __syncthreads();
  #pragma unroll
  for (int i = 0; i < 32; ++i) {
    int idx = i * 256 + t;
    X0[((size_t)row0 + (idx >> 7)) * 128 + (idx & 127)] = xl[idx >> 7][idx & 127];
  }
}

// ------- depthwise 3x3 conv over (a=5, p=4096) + SiLU, 4 outputs/thread -------
__global__ __launch_bounds__(256)
void k_conv(const float* __restrict__ X0, const float* __restrict__ cw,
            const float* __restrict__ cb, float* __restrict__ XT) {
  int g = blockIdx.x * 256 + threadIdx.x;   // B*LL*128/4 = 1,310,720
  int d = g & 127;
  int zz4 = g >> 7;                          // (b*LL + z0)/4
  int b = zz4 / (LL / 4);
  int r = zz4 - b * (LL / 4);
  int z0 = r * 4;
  int a = z0 >> 12, p = z0 & 4095;
  float w9[9];
  #pragma unroll
  for (int i = 0; i < 9; ++i) w9[i] = cw[d * 9 + i];
  float cbv = cb[d];
  float acc[4] = {cbv, cbv, cbv, cbv};
  #pragma unroll
  for (int di = 0; di < 3; ++di) {
    int aa = a + di - 1;
    if (aa < 0 || aa >= 5) continue;
    const float* rowb = X0 + ((size_t)b * LL + (size_t)aa * PIX) * 128 + d;
    #pragma unroll
    for (int dj = -1; dj <= 4; ++dj) {
      int pp = p + dj;
      if (pp < 0 || pp >= PIX) continue;
      float v = rowb[(size_t)pp * 128];
      #pragma unroll
      for (int o = 0; o < 4; ++o) {
        int rel = dj - o;
        if (rel >= -1 && rel <= 1) acc[o] = fmaf(w9[di * 3 + rel + 1], v, acc[o]);
      }
    }
  }
  float* dst = XT + (size_t)(zz4 * 4) * 128 + d;
  #pragma unroll
  for (int o = 0; o < 4; ++o) {
    float sg = 1.0f / (1.0f + __expf(-acc[o]));
    dst[(size_t)o * 128] = acc[o] * sg;
  }
}

// ---- x_proj GEMM, output permuted to scan order, split ZdtB[24] / ZC[16] ----
__global__ __launch_bounds__(256, 4)
void k_gemmZ(const float* __restrict__ X, const float* __restrict__ W,
             float* __restrict__ ZdtB, float* __restrict__ ZC) {
  __shared__ float xl[64][129];
  __shared__ __align__(16) float wlT[32][164];
  int t = threadIdx.x;
  int row0 = blockIdx.x * 64;
  #pragma unroll
  for (int i = 0; i < 32; ++i) {
    int idx = i * 256 + t;
    xl[idx >> 7][idx & 127] = X[((size_t)row0 + (idx >> 7)) * 128 + (idx & 127)];
  }
  int zl = t & 63, mg = t >> 6;
  float acc[40];
  #pragma unroll
  for (int i = 0; i < 40; ++i) acc[i] = 0.0f;
  for (int c0 = 0; c0 < 128; c0 += 32) {
    __syncthreads();
    #pragma unroll
    for (int i = 0; i < 20; ++i) {
      int m = (t >> 5) * 20 + i;
      wlT[t & 31][m] = W[(size_t)m * 128 + c0 + (t & 31)];
    }
    __syncthreads();
    for (int cc = 0; cc < 32; ++cc) {
      float xv = xl[zl][c0 + cc];
      const float4* wr = (const float4*)(&wlT[cc][mg * 40]);
      #pragma unroll
      for (int q = 0; q < 10; ++q) {
        float4 w4 = wr[q];
        acc[q*4+0] = fmaf(w4.x, xv, acc[q*4+0]);
        acc[q*4+1] = fmaf(w4.y, xv, acc[q*4+1]);
        acc[q*4+2] = fmaf(w4.z, xv, acc[q*4+2]);
        acc[q*4+3] = fmaf(w4.w, xv, acc[q*4+3]);
      }
    }
  }
  int row = row0 + zl;
  int b = row / LL, z = row - b * LL;
  int a = z >> 12, qq = z & 4095;
  int l;
  if (mg == 0)      l = z;
  else if (mg == 1) l = 5 * qq + a;
  else if (mg == 2) l = 20479 - z;
  else              l = 20479 - (5 * qq + a);
  float* dD = ZdtB + ((size_t)(b * 4 + mg) * LL + l) * 24;
  #pragma unroll
  for (int q2 = 0; q2 < 6; ++q2) {
    float4 v = make_float4(acc[q2*4], acc[q2*4+1], acc[q2*4+2], acc[q2*4+3]);
    *(float4*)(dD + q2 * 4) = v;
  }
  float* dC = ZC + ((size_t)(b * 4 + mg) * LL + l) * 16;
  #pragma unroll
  for (int q2 = 0; q2 < 4; ++q2) {
    float4 v = make_float4(acc[24+q2*4], acc[24+q2*4+1], acc[24+q2*4+2], acc[24+q2*4+3]);
    *(float4*)(dC + q2 * 4) = v;
  }
}

// ------- single-pass chunked selective scan (per-wave, barrier-free) -------
template<int K>
__device__ void scan_body(int b, int chunk, int dh, int lane,
    const float* __restrict__ XT, const float* __restrict__ ZdtB,
    const float* __restrict__ ZC,
    const float* __restrict__ dt_w, const float* __restrict__ dt_b,
    const float* __restrict__ A_logs, const float* __restrict__ Ds,
    float* __restrict__ h_out, float* __restrict__ sumdts,
    float* __restrict__ ysz, float* __restrict__ cumdtv,
    float* stD, float* stC, float* xs)
{
  const int d = dh * 64 + lane;
  const int kd = K * 128 + d;
  bool chainok = true;
  #pragma unroll
  for (int n = 0; n < NS; ++n) {
    float An = -__expf(A_logs[(size_t)kd * 16 + n]);
    chainok = chainok && (fabsf(An + (float)(n + 1)) < 3e-5f * (float)(n + 1));
  }
  v2f dw2[4];
  #pragma unroll
  for (int r = 0; r < 4; ++r) {
    dw2[r][0] = dt_w[(size_t)kd * 8 + 2 * r];
    dw2[r][1] = dt_w[(size_t)kd * 8 + 2 * r + 1];
  }
  const float dtb = dt_b[kd], dsv = Ds[kd];
  v2f h2[8];
  #pragma unroll
  for (int n = 0; n < 8; ++n) h2[n] = (v2f){0.0f, 0.0f};
  float sdt = 0.0f;
  const int seq = b * 4 + K;
  const float* ZDs = ZdtB + (size_t)seq * LL * 24;
  const float* ZCs = ZC + (size_t)seq * LL * 16;
  const float* Xb = XT + (size_t)b * LL * 128;
  float* ysb = ysz + (size_t)seq * PIX * 128;
  float* cdb = cumdtv + (size_t)seq * PIX * 128;
  const int l0 = chunk * LC;

  if (__all(chainok ? 1 : 0)) {
    #pragma unroll 1
    for (int sub = 0; sub < NSUB; ++sub) {
      const int ls = l0 + sub * SUBS;
      // stage dt/B rows (SUBS*24=384 floats) via per-wave LDS (wave-synchronous)
      {
        const v2f* srcD = (const v2f*)(ZDs + (size_t)ls * 24);
        v2f* dstD = (v2f*)stD;
        #pragma unroll
        for (int i = 0; i < 3; ++i) dstD[i * 64 + lane] = srcD[i * 64 + lane];
      }
      int s0c = 0;
      bool needC;
      if (K == 0)      needC = (ls < PIX);
      else if (K == 2) needC = (ls + SUBS > LL - PIX);
      else             needC = true;
      if (K == 1) s0c = (5 - (ls % 5)) % 5;
      if (K == 3) s0c = (9 - (ls % 5)) % 5;
      if (needC) {
        if (K == 0 || K == 2) {
          const v2f* srcC = (const v2f*)(ZCs + (size_t)ls * 16);
          v2f* dstC = (v2f*)stC;
          #pragma unroll
          for (int i = 0; i < 2; ++i) dstC[i * 64 + lane] = srcC[i * 64 + lane];
        } else {
          int j = lane >> 4, col = lane & 15;
          int l = ls + s0c + 5 * j;
          if (l > LL - 1) l = LL - 1;
          stC[lane] = ZCs[(size_t)l * 16 + col];
        }
      }
      // LDS-stage x for SUBS steps (per-wave slab)
      #pragma unroll
      for (int s = 0; s < SUBS; ++s) {
        int z = zmapT<K>(ls + s);
        xs[s * 64 + lane] = Xb[(size_t)z * 128 + d];
      }
      int zc = 0;
      if (K == 1) zc = (ls + s0c) / 5;
      if (K == 3) zc = (20479 - ls - s0c) / 5;
      int yj = 0;
      #pragma unroll
      for (int s = 0; s < SUBS; ++s) {
        const v2f* rowD = (const v2f*)(stD + s * 24);
        v2f zd0 = rowD[0], zd1 = rowD[1], zd2 = rowD[2], zd3 = rowD[3];
        v2f da = pk_mul(dw2[0], zd0);
        PK_FMA_ACC(da, dw2[1], zd1);
        PK_FMA_ACC(da, dw2[2], zd2);
        PK_FMA_ACC(da, dw2[3], zd3);
        float dtl = dtb + da[0] + da[1];
        float edt = __expf(dtl);
        float e1 = __builtin_amdgcn_rcpf(1.0f + edt);  // exp(-softplus(dtl))
        float dt = (dtl > 20.0f) ? dtl : __logf(1.0f + edt);
        sdt += dt;
        float xsv = xs[s * 64 + lane];
        float dtx = dt * xsv;
        v2f dtx2 = {dtx, dtx};
        float e2 = e1 * e1;
        v2f E[8];
        E[0] = (v2f){e1, e2};
        v2f e2s = {e2, e2};
        E[1] = pk_mul(E[0], e2s);   // e3,e4
        E[2] = pk_mul(E[1], e2s);   // e5,e6
        E[3] = pk_mul(E[2], e2s);   // e7,e8
        float e8 = E[3][1];
        v2f e8s = {e8, e8};
        E[4] = pk_mul(E[0], e8s);
        E[5] = pk_mul(E[1], e8s);
        E[6] = pk_mul(E[2], e8s);
        E[7] = pk_mul(E[3], e8s);
        const v2f* B2 = (const v2f*)(stD + s * 24 + 8);
        #pragma unroll
        for (int i = 0; i < 8; ++i) {
          v2f m = pk_mul(dtx2, B2[i]);
          PK_DECAY(h2[i], E[i], m);
        }
        bool doY;
        int z;
        if (K == 0)      { z = ls + s;            doY = (z < PIX); }
        else if (K == 2) { z = 20479 - (ls + s);  doY = (z < PIX); }
        else             { z = zc;                doY = ((s % 5) == s0c); }
        if (doY) {
          const v2f* C2 = (const v2f*)(stC + ((K == 0 || K == 2) ? s : yj) * 16);
          v2f ya = pk_mul(h2[0], C2[0]);
          #pragma unroll
          for (int i = 1; i < 8; ++i) PK_FMA_ACC(ya, h2[i], C2[i]);
          float y = fmaf(dsv, xsv, ya[0] + ya[1]);
          size_t o = (size_t)z * 128 + d;
          ysb[o] = y;
          cdb[o] = sdt;
          ++yj;
          if (K == 1) ++zc;
          if (K == 3) --zc;
        }
      }
    }
  } else {
    // general fallback (compact, never taken for this A_logs)
    float An[NS];
    #pragma unroll
    for (int n = 0; n < NS; ++n) An[n] = -__expf(A_logs[(size_t)kd * 16 + n]);
    float hs[NS];
    #pragma unroll
    for (int n = 0; n < NS; ++n) hs[n] = 0.0f;
    #pragma unroll 1
    for (int l = l0; l < l0 + LC; ++l) {
      int z = zmapT<K>(l);
      const float* rowD = ZDs + (size_t)l * 24;
      float dtl = dtb;
      #pragma unroll
      for (int r = 0; r < RR; ++r) dtl += dt_w[(size_t)kd * 8 + r] * rowD[r];
      float edt = __expf(dtl);
      float dt = (dtl > 20.0f) ? dtl : __logf(1.0f + edt);
      sdt += dt;
      float xv = Xb[(size_t)z * 128 + d];
      float dtx = dt * xv;
      #pragma unroll
      for (int n = 0; n < NS; ++n)
        hs[n] = hs[n] * __expf(dt * An[n]) + dtx * rowD[8 + n];
      if (z < PIX) {
        const float* rowC = ZCs + (size_t)l * 16;
        float y = dsv * xv;
        #pragma unroll
        for (int n = 0; n < NS; ++n) y = fmaf(hs[n], rowC[n], y);
        size_t o = (size_t)z * 128 + d;
        ysb[o] = y;
        cdb[o] = sdt;
      }
    }
    #pragma unroll
    for (int n = 0; n < 8; ++n) h2[n] = (v2f){hs[2*n], hs[2*n+1]};
  }
  float* ho = h_out + (((size_t)seq * NCHK + chunk) * 128 + d) * 16;
  #pragma unroll
  for (int n = 0; n < 8; ++n) {
    ho[2*n] = h2[n][0];
    ho[2*n+1] = h2[n][1];
  }
  sumdts[((size_t)seq * NCHK + chunk) * 128 + d] = sdt;
}

__global__ __launch_bounds__(256, 5)
void k_scan1(const float* __restrict__ XT, const float* __restrict__ ZdtB,
             const float* __restrict__ ZC,
             const float* __restrict__ dt_w, const float* __restrict__ dt_b,
             const float* __restrict__ A_logs, const float* __restrict__ Ds,
             float* __restrict__ h_out, float* __restrict__ sumdts,
             float* __restrict__ ysz, float* __restrict__ cumdtv) {
  __shared__ __align__(16) float stD_all[4][SUBS * 24];
  __shared__ __align__(16) float stC_all[4][SUBS * 16];
  __shared__ __align__(16) float xs_all[4][SUBS * 64];
  int tid = threadIdx.x, wid = tid >> 6, lane = tid & 63;
  int bid = blockIdx.x;            // B * (K0CP + 3*128) = 820
  int bb = bid / (K0CP + 384);
  int idx = bid - bb * (K0CP + 384);
  int k, cp;
  if (idx < K0CP)            { k = 0; cp = idx; }
  else if (idx < K0CP + 128) { k = 1; cp = idx - K0CP; }
  else if (idx < K0CP + 256) { k = 2; cp = idx - (K0CP + 128); }
  else                       { k = 3; cp = idx - (K0CP + 256); }
  int chunk = cp * 2 + (wid >> 1);
  int dh = wid & 1;
  float* stD = stD_all[wid];
  float* stC = stC_all[wid];
  float* xs  = xs_all[wid];
  switch (k) {
    case 0: scan_body<0>(bb, chunk, dh, lane, XT, ZdtB, ZC, dt_w, dt_b, A_logs, Ds, h_out, sumdts, ysz, cumdtv, stD, stC, xs); break;
    case 1: scan_body<1>(bb, chunk, dh, lane, XT, ZdtB, ZC, dt_w, dt_b, A_logs, Ds, h_out, sumdts, ysz, cumdtv, stD, stC, xs); break;
    case 2: scan_body<2>(bb, chunk, dh, lane, XT, ZdtB, ZC, dt_w, dt_b, A_logs, Ds, h_out, sumdts, ysz, cumdtv, stD, stC, xs); break;
    default: scan_body<3>(bb, chunk, dh, lane, XT, ZdtB, ZC, dt_w, dt_b, A_logs, Ds, h_out, sumdts, ysz, cumdtv, stD, stC, xs); break;
  }
}

// ---- combine level A: per-group affine fold (Ag = prod a, Bg = fold b) ----
__global__ __launch_bounds__(256)
void k_comb_a(const float* __restrict__ A_logs, const float* __restrict__ sumdts,
              const float* __restrict__ h_out, float* __restrict__ Ag,
              float* __restrict__ Bg) {
  int g = blockIdx.x * 256 + threadIdx.x;   // 8*16*128*16 = 262144
  int n = g & 15;
  int d = (g >> 4) & 127;
  int grp = (g >> 11) & 15;
  int seq = g >> 15;
  int k = seq & 3;
  float An = -__expf(A_logs[(size_t)(k * 128 + d) * 16 + n]);
  float A = 1.0f, Bv = 0.0f;
  size_t cbase = (size_t)seq * NCHK + grp * GCH;
  #pragma unroll 4
  for (int j = 0; j < GCH; ++j) {
    float a = __expf(An * sumdts[(cbase + j) * 128 + d]);
    float b = h_out[((cbase + j) * 128 + d) * 16 + n];
    A *= a;
    Bv = Bv * a + b;
  }
  size_t o = (((size_t)seq * NGRP + grp) * 128 + d) * 16 + n;
  Ag[o] = A;
  Bg[o] = Bv;
}

// ---- combine level B: prefix over 16 groups ----
__global__ __launch_bounds__(256)
void k_comb_b(const float* __restrict__ Ag, const float* __restrict__ Bg,
              float* __restrict__ Hg) {
  int g = blockIdx.x * 256 + threadIdx.x;   // 8*128*16 = 16384
  int n = g & 15;
  int d = (g >> 4) & 127;
  int seq = g >> 11;
  float H = 0.0f;
  #pragma unroll
  for (int grp = 0; grp < NGRP; ++grp) {
    size_t o = (((size_t)seq * NGRP + grp) * 128 + d) * 16 + n;
    Hg[o] = H;
    H = Ag[o] * H + Bg[o];
  }
}

// ---- combine level C: replay within group -> h_in per chunk ----
__global__ __launch_bounds__(256)
void k_comb_c(const float* __restrict__ A_logs, const float* __restrict__ sumdts,
              const float* __restrict__ h_out, const float* __restrict__ Hg,
              float* __restrict__ h_in) {
  int g = blockIdx.x * 256 + threadIdx.x;   // 262144
  int n = g & 15;
  int d = (g >> 4) & 127;
  int grp = (g >> 11) & 15;
  int seq = g >> 15;
  int k = seq & 3;
  float An = -__expf(A_logs[(size_t)(k * 128 + d) * 16 + n]);
  float h = Hg[(((size_t)seq * NGRP + grp) * 128 + d) * 16 + n];
  size_t cbase = (size_t)seq * NCHK + grp * GCH;
  #pragma unroll 4
  for (int j = 0; j < GCH; ++j) {
    size_t o = ((cbase + j) * 128 + d) * 16 + n;
    h_in[o] = h;
    float a = __expf(An * sumdts[(cbase + j) * 128 + d]);
    h = a * h + h_out[o];
  }
}

// ---------------- transpose out_proj_w ----------------
__global__ __launch_bounds__(256)
void k_wt(const float* __restrict__ Wo, float* __restrict__ WT) {
  __shared__ float tl[32][33];
  int bx = blockIdx.x & 3, by = blockIdx.x >> 2;
  int t = threadIdx.x;
  int tx = t & 31, ty = t >> 5;
  #pragma unroll
  for (int i = 0; i < 4; ++i)
    tl[ty + i * 8][tx] = Wo[(size_t)(by * 32 + ty + i * 8) * 128 + bx * 32 + tx];
  __syncthreads();
  #pragma unroll
  for (int i = 0; i < 4; ++i)
    WT[(size_t)(bx * 32 + ty + i * 8) * 128 + by * 32 + tx] = tl[tx][ty + i * 8];
}

// ------- merge 4 dirs + cross-chunk fix + LayerNorm + out_proj -------
__global__ __launch_bounds__(256)
void k_merge(const float* __restrict__ ysz, const float* __restrict__ ZC,
             const float* __restrict__ A_logs, const float* __restrict__ h_in,
             const float* __restrict__ cumdt,
             const float* __restrict__ ln_g, const float* __restrict__ ln_b,
             const float* __restrict__ WT, float* __restrict__ out) {
  __shared__ __align__(16) float ynT[128][20];
  __shared__ float red[4][8][2];
  int blk = blockIdx.x;          // 512: b = blk>>8, ptile = blk&255
  int b = blk >> 8;
  int p0 = (blk & 255) * 16;
  int tid = threadIdx.x;
  int t = tid & 127;             // channel d
  int half = tid >> 7;           // 0/1
  int w = tid >> 6;              // wave 0..3
  float g = ln_g[t], bb = ln_b[t];
  bool cok[4];
  #pragma unroll
  for (int k = 0; k < 4; ++k) {
    bool c = true;
    #pragma unroll
    for (int n = 0; n < NS; ++n) {
      float An = -__expf(A_logs[(size_t)(k * 128 + t) * 16 + n]);
      c = c && (fabsf(An + (float)(n + 1)) < 3e-5f * (float)(n + 1));
    }
    cok[k] = c;
  }
  float yv[8];
  #pragma unroll
  for (int i = 0; i < 8; ++i) {
    int p = p0 + 2 * i + half;
    float y = 0.0f;
    #pragma unroll
    for (int k = 0; k < 4; ++k) {
      size_t zi = ((size_t)(b * 4 + k) * PIX + p) * 128 + t;
      float yk = ysz[zi];
      int l;
      if (k == 0)      l = p;
      else if (k == 1) l = 5 * p;
      else if (k == 2) l = 20479 - p;
      else             l = 20479 - 5 * p;
      int chunk = l / LC;
      float cd = cumdt[zi];
      const v2f* hi2 = (const v2f*)(h_in + (((size_t)(b * 4 + k) * NCHK + chunk) * 128 + t) * 16);
      const v2f* Cr2 = (const v2f*)(ZC + ((size_t)(b * 4 + k) * LL + l) * 16);
      float fix;
      if (cok[k]) {
        float q = __expf(-cd);
        float q2 = q * q;
        v2f Q[8];
        Q[0] = (v2f){q, q2};
        v2f q2s = {q2, q2};
        Q[1] = pk_mul(Q[0], q2s);
        Q[2] = pk_mul(Q[1], q2s);
        Q[3] = pk_mul(Q[2], q2s);
        float q8 = Q[3][1];
        v2f q8s = {q8, q8};
        Q[4] = pk_mul(Q[0], q8s);
        Q[5] = pk_mul(Q[1], q8s);
        Q[6] = pk_mul(Q[2], q8s);
        Q[7] = pk_mul(Q[3], q8s);
        v2f a = pk_mul(pk_mul(hi2[0], Cr2[0]), Q[0]);
        #pragma unroll
        for (int j = 1; j < 8; ++j) {
          v2f m = pk_mul(hi2[j], Cr2[j]);
          PK_FMA_ACC(a, m, Q[j]);
        }
        fix = a[0] + a[1];
      } else {
        fix = 0.0f;
        const float* hi = (const float*)hi2;
        const float* Cr = (const float*)Cr2;
        #pragma unroll
        for (int n = 0; n < NS; ++n) {
          float An = -__expf(A_logs[(size_t)(k * 128 + t) * 16 + n]);
          fix += Cr[n] * hi[n] * __expf(An * cd);
        }
      }
      y += yk + fix;
    }
    yv[i] = y;
    float s1 = y, s2 = y * y;
    #pragma unroll
    for (int off = 32; off; off >>= 1) {
      s1 += __shfl_xor(s1, off);
      s2 += __shfl_xor(s2, off);
    }
    if ((tid & 63) == 0) { red[w][i][0] = s1; red[w][i][1] = s2; }
  }
  __syncthreads();
  #pragma unroll
  for (int i = 0; i < 8; ++i) {
    int pl = 2 * i + half;
    float S1 = red[half * 2][i][0] + red[half * 2 + 1][i][0];
    float S2 = red[half * 2][i][1] + red[half * 2 + 1][i][1];
    float mu = S1 * (1.0f / 128.0f);
    float var = S2 * (1.0f / 128.0f) - mu * mu;
    float rs = rsqrtf(var + 1e-5f);
    ynT[t][pl] = (yv[i] - mu) * rs * g + bb;
  }
  __syncthreads();
  float acc[8];
  #pragma unroll
  for (int i = 0; i < 8; ++i) acc[i] = 0.0f;
  for (int dd = 0; dd < 128; ++dd) {
    float wv = WT[(size_t)dd * 128 + t];
    const float4* yr = (const float4*)(&ynT[dd][half * 8]);
    float4 ya = yr[0], yb4 = yr[1];
    acc[0] = fmaf(ya.x,  wv, acc[0]);
    acc[1] = fmaf(ya.y,  wv, acc[1]);
    acc[2] = fmaf(ya.z,  wv, acc[2]);
    acc[3] = fmaf(ya.w,  wv, acc[3]);
    acc[4] = fmaf(yb4.x, wv, acc[4]);
    acc[5] = fmaf(yb4.y, wv, acc[5]);
    acc[6] = fmaf(yb4.z, wv, acc[6]);
    acc[7] = fmaf(yb4.w, wv, acc[7]);
  }
  float* dst = out + ((size_t)b * 128 + t) * PIX + p0 + half * 8;
  float4 v0 = make_float4(acc[0], acc[1], acc[2], acc[3]);
  float4 v1 = make_float4(acc[4], acc[5], acc[6], acc[7]);
  *(float4*)(dst) = v0;
  *(float4*)(dst + 4) = v1;
}

extern "C" void kernel_launch(void* const* d_in, const int* in_sizes, int n_in,
                              void* d_out, int out_size, void* d_ws, size_t ws_size,
                              hipStream_t stream) {
  const float* x         = (const float*)d_in[0];
  // d_in[1] record_len unused
  const float* nam       = (const float*)d_in[2];
  const float* in_proj_w = (const float*)d_in[3];
  const float* conv_w    = (const float*)d_in[4];
  const float* conv_b    = (const float*)d_in[5];
  const float* x_proj_w  = (const float*)d_in[6];
  const float* dt_w      = (const float*)d_in[7];
  const float* dt_b      = (const float*)d_in[8];
  const float* A_logs    = (const float*)d_in[9];
  const float* Ds        = (const float*)d_in[10];
  const float* ln_g      = (const float*)d_in[11];
  const float* ln_b      = (const float*)d_in[12];
  const float* out_proj_w= (const float*)d_in[13];
  float* out = (float*)d_out;
  float* ws  = (float*)d_ws;

  // workspace layout (floats)
  float* warped = ws;                          // 5,242,880 (later: h_out 4.2M)
  float* alpha  = warped + 5242880;            //    40,960
  float* X0     = alpha  + 40960;              // 5,242,880 (later: h_in 4.2M)
  float* XT     = X0     + 5242880;            // 5,242,880
  float* ZdtB   = XT     + 5242880;            // 3,932,160
  float* ZC     = ZdtB   + 3932160;            // 2,621,440
  float* sums   = ZC     + 2621440;            //   262,144
  float* ysz    = sums   + 262144;             // 4,194,304
  float* cumdt  = ysz    + 4194304;            // 4,194,304
  float* WT     = cumdt  + 4194304;            //    16,384
  float* Ag     = WT     + 16384;              //   262,144
  float* Bg     = Ag     + 262144;             //   262,144
  float* Hg     = Bg     + 262144;             //   262,144

  float* h_out = warped;   // warped dead after k_gemm_in
  float* h_in  = X0;       // X0 dead after k_conv

  k_warp   <<<20480, 256, 0, stream>>>(x, nam, warped);
  k_alpha  <<<128,   512, 0, stream>>>(warped, nam, alpha);
  k_gemm_in<<<640,   256, 0, stream>>>(warped, alpha, in_proj_w, X0);
  k_conv   <<<5120,  256, 0, stream>>>(X0, conv_w, conv_b, XT);
  k_gemmZ  <<<640,   256, 0, stream>>>(XT, x_proj_w, ZdtB, ZC);
  k_scan1  <<<2 * (K0CP + 384), 256, 0, stream>>>(XT, ZdtB, ZC, dt_w, dt_b,
                                                  A_logs, Ds, h_out, sums, ysz, cumdt);
  k_comb_a <<<1024,  256, 0, stream>>>(A_logs, sums, h_out, Ag, Bg);
  k_comb_b <<<64,    256, 0, stream>>>(Ag, Bg, Hg);
  k_comb_c <<<1024,  256, 0, stream>>>(A_logs, sums, h_out, Hg, h_in);
  k_wt     <<<16,    256, 0, stream>>>(out_proj_w, WT);
  k_merge  <<<512,   256, 0, stream>>>(ysz, ZC, A_logs, h_in, cumdt,
                                       ln_g, ln_b, WT, out);
}

// Round 6
// 256.778 us; speedup vs baseline: 2.6013x; 1.1138x over previous
//
#include <hip/hip_runtime.h>
#include <math.h>

#define B_S   2
#define PIX   4096
#define LL    20480
#define NS    16
#define RR    8
#define NCHK  512     // chunks per sequence
#define LC    40      // steps per chunk
#define SUBS  10      // steps per staging sub-chunk
#define NSUB  4       // LC/SUBS
#define NGRP  32      // chunk groups for combine
#define GCH   16      // chunks per group
#define K0CP  52      // chunk-pairs kept for K=0 (chunks 0..103 cover l<4160)

typedef float v2f __attribute__((ext_vector_type(2)));

__device__ __forceinline__ v2f pk_mul(v2f a, v2f b) {
  v2f d;
  asm("v_pk_mul_f32 %0, %1, %2" : "=v"(d) : "v"(a), "v"(b));
  return d;
}
// a = b*c + a
#define PK_FMA_ACC(a, b, c) asm("v_pk_fma_f32 %0, %1, %2, %0" : "+v"(a) : "v"(b), "v"(c))
// h = h*e + m
#define PK_DECAY(h, e, m) asm("v_pk_fma_f32 %0, %0, %1, %2" : "+v"(h) : "v"(e), "v"(m))

template<int K>
__device__ __forceinline__ int zmapT(int l) {
  if (K == 0) return l;
  if (K == 1) return ((l % 5) << 12) + l / 5;
  if (K == 2) return 20479 - l;
  int lr = 20479 - l;
  return ((lr % 5) << 12) + lr / 5;
}

// ---------------- affine grid + bilinear grid_sample ----------------
__global__ __launch_bounds__(256)
void k_warp(const float* __restrict__ x, const float* __restrict__ nam,
            float* __restrict__ warped) {
  int g = blockIdx.x * 256 + threadIdx.x;        // B*K*C*PIX = 5,242,880
  int p  = g & 4095;
  int c  = (g >> 12) & 127;
  int bk = g >> 19;                              // 0..9
  int b = bk / 5, k = bk - b * 5;
  const float* th = nam + (size_t)(b * 25 + k) * 6;   // nam[b,0,k]
  float gx = ((p & 63) + 0.5f) * 0.03125f - 1.0f;
  float gy = ((p >> 6) + 0.5f) * 0.03125f - 1.0f;
  float grx = th[0] * gx + th[1] * gy + th[2];
  float gry = th[3] * gx + th[4] * gy + th[5];
  float ix = ((grx + 1.0f) * 64.0f - 1.0f) * 0.5f;
  float iy = ((gry + 1.0f) * 64.0f - 1.0f) * 0.5f;
  float x0 = floorf(ix), y0 = floorf(iy);
  float fx = ix - x0,  fy = iy - y0;
  const float* src = x + (size_t)(bk * 128 + c) * PIX;
  float acc = 0.0f;
  #pragma unroll
  for (int dy = 0; dy < 2; ++dy) {
    float yf = y0 + dy;
    float wy = dy ? fy : 1.0f - fy;
    if (yf < 0.0f || yf > 63.0f) continue;
    int yi = (int)yf;
    #pragma unroll
    for (int dx = 0; dx < 2; ++dx) {
      float xf = x0 + dx;
      float wx = dx ? fx : 1.0f - fx;
      if (xf < 0.0f || xf > 63.0f) continue;
      acc += wx * wy * src[yi * 64 + (int)xf];
    }
  }
  warped[g] = acc;
}

// ---------------- per-pixel similarity -> softmax alpha ----------------
__global__ __launch_bounds__(512)
void k_alpha(const float* __restrict__ warped, const float* __restrict__ nam,
             float* __restrict__ alpha) {
  __shared__ float part[8][64][9];
  int blk = blockIdx.x;            // 128 blocks
  int b = blk >> 6;
  int p0 = (blk & 63) << 6;
  int wv = threadIdx.x >> 6, lane = threadIdx.x & 63;
  int p = p0 + lane;
  const float* wb = warped + (size_t)b * 5 * 128 * PIX + p;
  float dot[5] = {0,0,0,0,0}, ssq[5] = {0,0,0,0,0};
  int c0 = wv * 16;
  for (int c = c0; c < c0 + 16; ++c) {
    float w0 = wb[(size_t)c * PIX];
    ssq[0] += w0 * w0;
    #pragma unroll
    for (int k = 1; k < 5; ++k) {
      float wk = wb[((size_t)k * 128 + c) * PIX];
      dot[k] += w0 * wk;
      ssq[k] += wk * wk;
    }
  }
  part[wv][lane][0] = ssq[0];
  #pragma unroll
  for (int k = 1; k < 5; ++k) {
    part[wv][lane][k] = dot[k];
    part[wv][lane][4 + k] = ssq[k];
  }
  __syncthreads();
  if (threadIdx.x < 64) {
    float q[9];
    #pragma unroll
    for (int j = 0; j < 9; ++j) {
      float s = 0.0f;
      #pragma unroll
      for (int w = 0; w < 8; ++w) s += part[w][lane][j];
      q[j] = s;
    }
    float n0 = fmaxf(sqrtf(q[0]), 1e-6f);
    float logit[5];
    #pragma unroll
    for (int k = 0; k < 5; ++k) {
      float dotk = (k == 0) ? q[0] : q[k];
      float ssqk = (k == 0) ? q[0] : q[4 + k];
      float nk = fmaxf(sqrtf(ssqk), 1e-6f);
      float sim = fminf(fmaxf(dotk / (n0 * nk), -1.0f), 1.0f);
      float r = fmaxf(1.0f - sim, 0.0f);
      float xr = r * (1.0f / 0.3f);
      float tt = fmaxf(1.0f - xr * xr, 0.0f);
      float wp = fmaxf(tt * tt, 1e-6f);
      const float* th = nam + (size_t)(b * 25 + k) * 6;
      float tx = th[2], ty = th[5];
      float yaw = fabsf(atan2f(th[1], th[0]));
      float gk = 1.0f / (1.0f + __expf(-(2.0f - 0.4f * sqrtf(tx*tx + ty*ty) - 0.8f * yaw)));
      logit[k] = __logf(wp + 1e-8f) + __logf(gk + 1e-8f);
    }
    float m = logit[0];
    #pragma unroll
    for (int k = 1; k < 5; ++k) m = fmaxf(m, logit[k]);
    float e[5], s = 0.0f;
    #pragma unroll
    for (int k = 0; k < 5; ++k) { e[k] = __expf(logit[k] - m); s += e[k]; }
    float inv = 1.0f / s;
    #pragma unroll
    for (int k = 0; k < 5; ++k)
      alpha[((size_t)(b * 5 + k)) * PIX + p] = e[k] * inv;
  }
}

// ---- in_proj GEMM fused with tokens transpose, 2 rows/thread ----
__global__ __launch_bounds__(256, 4)
void k_gemm_in(const float* __restrict__ warped, const float* __restrict__ alpha,
               const float* __restrict__ W, float* __restrict__ X0) {
  __shared__ float xl[64][129];
  __shared__ __align__(16) float wlT[32][132];
  int t = threadIdx.x;
  int row0 = blockIdx.x * 64;             // 640 blocks, rows = b*LL + a*4096 + p
  int b = row0 / LL;
  int z0 = row0 - b * LL;
  int a = z0 >> 12;
  int p0 = z0 & 4095;
  int ba = b * 5 + a;
  int r = t & 63, cg = t >> 6;
  float av = alpha[(size_t)ba * PIX + p0 + r];
  #pragma unroll
  for (int i = 0; i < 32; ++i) {
    int c = cg * 32 + i;
    xl[r][c] = warped[((size_t)ba * 128 + c) * PIX + p0 + r] * av;
  }
  int zl2 = t & 31;          // rows 2*zl2, 2*zl2+1
  int mg  = t >> 5;          // 0..7, cols mg*16..+16
  float acc0[16], acc1[16];
  #pragma unroll
  for (int i = 0; i < 16; ++i) { acc0[i] = 0.0f; acc1[i] = 0.0f; }
  for (int c0 = 0; c0 < 128; c0 += 32) {
    __syncthreads();
    #pragma unroll
    for (int i = 0; i < 16; ++i) {
      int m = (t >> 5) * 16 + i;
      wlT[t & 31][m] = W[(size_t)m * 128 + c0 + (t & 31)];
    }
    __syncthreads();
    const float* xr0 = xl[2 * zl2];
    const float* xr1 = xl[2 * zl2 + 1];
    for (int cc = 0; cc < 32; ++cc) {
      float xv0 = xr0[c0 + cc];
      float xv1 = xr1[c0 + cc];
      const float4* wr = (const float4*)(&wlT[cc][mg * 16]);
      #pragma unroll
      for (int q = 0; q < 4; ++q) {
        float4 w4 = wr[q];
        acc0[q*4+0] = fmaf(w4.x, xv0, acc0[q*4+0]);
        acc0[q*4+1] = fmaf(w4.y, xv0, acc0[q*4+1]);
        acc0[q*4+2] = fmaf(w4.z, xv0, acc0[q*4+2]);
        acc0[q*4+3] = fmaf(w4.w, xv0, acc0[q*4+3]);
        acc1[q*4+0] = fmaf(w4.x, xv1, acc1[q*4+0]);
        acc1[q*4+1] = fmaf(w4.y, xv1, acc1[q*4+1]);
        acc1[q*4+2] = fmaf(w4.z, xv1, acc1[q*4+2]);
        acc1[q*4+3] = fmaf(w4.w, xv1, acc1[q*4+3]);
      }
    }
  }
  __syncthreads();
  #pragma unroll
  for (int q = 0; q < 16; ++q) {
    xl[2 * zl2][mg * 16 + q] = acc0[q];
    xl[2 * zl2 + 1][mg * 16 + q] = acc1[q];
  }
  __syncthreads();
  #pragma unroll
  for (int i = 0; i < 32; ++i) {
    int idx = i * 256 + t;
    X0[((size_t)row0 + (idx >> 7)) * 128 + (idx & 127)] = xl[idx >> 7][idx & 127];
  }
}

// ------- depthwise 3x3 conv over (a=5, p=4096) + SiLU, 4 outputs/thread -------
__global__ __launch_bounds__(256)
void k_conv(const float* __restrict__ X0, const float* __restrict__ cw,
            const float* __restrict__ cb, float* __restrict__ XT) {
  int g = blockIdx.x * 256 + threadIdx.x;   // B*LL*128/4 = 1,310,720
  int d = g & 127;
  int zz4 = g >> 7;                          // (b*LL + z0)/4
  int b = zz4 / (LL / 4);
  int r = zz4 - b * (LL / 4);
  int z0 = r * 4;
  int a = z0 >> 12, p = z0 & 4095;
  float w9[9];
  #pragma unroll
  for (int i = 0; i < 9; ++i) w9[i] = cw[d * 9 + i];
  float cbv = cb[d];
  float acc[4] = {cbv, cbv, cbv, cbv};
  #pragma unroll
  for (int di = 0; di < 3; ++di) {
    int aa = a + di - 1;
    if (aa < 0 || aa >= 5) continue;
    const float* rowb = X0 + ((size_t)b * LL + (size_t)aa * PIX) * 128 + d;
    #pragma unroll
    for (int dj = -1; dj <= 4; ++dj) {
      int pp = p + dj;
      if (pp < 0 || pp >= PIX) continue;
      float v = rowb[(size_t)pp * 128];
      #pragma unroll
      for (int o = 0; o < 4; ++o) {
        int rel = dj - o;
        if (rel >= -1 && rel <= 1) acc[o] = fmaf(w9[di * 3 + rel + 1], v, acc[o]);
      }
    }
  }
  float* dst = XT + (size_t)(zz4 * 4) * 128 + d;
  #pragma unroll
  for (int o = 0; o < 4; ++o) {
    float sg = 1.0f / (1.0f + __expf(-acc[o]));
    dst[(size_t)o * 128] = acc[o] * sg;
  }
}

// ---- x_proj GEMM (2 rows/thread), output permuted to scan order ----
__global__ __launch_bounds__(256, 4)
void k_gemmZ(const float* __restrict__ X, const float* __restrict__ W,
             float* __restrict__ ZdtB, float* __restrict__ ZC) {
  __shared__ float xl[64][129];
  __shared__ __align__(16) float wlT[32][164];
  int t = threadIdx.x;
  int row0 = blockIdx.x * 64;
  #pragma unroll
  for (int i = 0; i < 32; ++i) {
    int idx = i * 256 + t;
    xl[idx >> 7][idx & 127] = X[((size_t)row0 + (idx >> 7)) * 128 + (idx & 127)];
  }
  int zl2 = t & 31;          // rows 2*zl2, 2*zl2+1
  int mg  = t >> 5;          // 0..7: dir = mg>>1, col half = mg&1 (20 cols)
  float acc0[20], acc1[20];
  #pragma unroll
  for (int i = 0; i < 20; ++i) { acc0[i] = 0.0f; acc1[i] = 0.0f; }
  for (int c0 = 0; c0 < 128; c0 += 32) {
    __syncthreads();
    #pragma unroll
    for (int i = 0; i < 20; ++i) {
      int m = (t >> 5) * 20 + i;
      wlT[t & 31][m] = W[(size_t)m * 128 + c0 + (t & 31)];
    }
    __syncthreads();
    const float* xr0 = xl[2 * zl2];
    const float* xr1 = xl[2 * zl2 + 1];
    for (int cc = 0; cc < 32; ++cc) {
      float xv0 = xr0[c0 + cc];
      float xv1 = xr1[c0 + cc];
      const float4* wr = (const float4*)(&wlT[cc][mg * 20]);
      #pragma unroll
      for (int q = 0; q < 5; ++q) {
        float4 w4 = wr[q];
        acc0[q*4+0] = fmaf(w4.x, xv0, acc0[q*4+0]);
        acc0[q*4+1] = fmaf(w4.y, xv0, acc0[q*4+1]);
        acc0[q*4+2] = fmaf(w4.z, xv0, acc0[q*4+2]);
        acc0[q*4+3] = fmaf(w4.w, xv0, acc0[q*4+3]);
        acc1[q*4+0] = fmaf(w4.x, xv1, acc1[q*4+0]);
        acc1[q*4+1] = fmaf(w4.y, xv1, acc1[q*4+1]);
        acc1[q*4+2] = fmaf(w4.z, xv1, acc1[q*4+2]);
        acc1[q*4+3] = fmaf(w4.w, xv1, acc1[q*4+3]);
      }
    }
  }
  int dir = mg >> 1;
  int halfc = mg & 1;
  #pragma unroll
  for (int rr = 0; rr < 2; ++rr) {
    const float* acc = rr ? acc1 : acc0;
    int row = row0 + 2 * zl2 + rr;
    int b = row / LL, z = row - b * LL;
    int a = z >> 12, qq = z & 4095;
    int l;
    if (dir == 0)      l = z;
    else if (dir == 1) l = 5 * qq + a;
    else if (dir == 2) l = 20479 - z;
    else               l = 20479 - (5 * qq + a);
    size_t seqrow = (size_t)(b * 4 + dir) * LL + l;
    if (halfc == 0) {
      float* dD = ZdtB + seqrow * 24;
      #pragma unroll
      for (int q2 = 0; q2 < 5; ++q2)
        *(float4*)(dD + q2 * 4) = make_float4(acc[q2*4], acc[q2*4+1], acc[q2*4+2], acc[q2*4+3]);
    } else {
      float* dD = ZdtB + seqrow * 24;
      *(float4*)(dD + 20) = make_float4(acc[0], acc[1], acc[2], acc[3]);
      float* dC = ZC + seqrow * 16;
      #pragma unroll
      for (int q2 = 0; q2 < 4; ++q2)
        *(float4*)(dC + q2 * 4) = make_float4(acc[4+q2*4], acc[4+q2*4+1], acc[4+q2*4+2], acc[4+q2*4+3]);
    }
  }
}

// ------- single-pass chunked selective scan (per-wave, barrier-free) -------
template<int K>
__device__ void scan_body(int b, int chunk, int dh, int lane,
    const float* __restrict__ XT, const float* __restrict__ ZdtB,
    const float* __restrict__ ZC,
    const float* __restrict__ dt_w, const float* __restrict__ dt_b,
    const float* __restrict__ A_logs, const float* __restrict__ Ds,
    float* __restrict__ h_out, float* __restrict__ sumdts,
    float* __restrict__ ysz, float* __restrict__ cumdtv,
    float* stD, float* stC, float* xs)
{
  const int d = dh * 64 + lane;
  const int kd = K * 128 + d;
  bool chainok = true;
  #pragma unroll
  for (int n = 0; n < NS; ++n) {
    float An = -__expf(A_logs[(size_t)kd * 16 + n]);
    chainok = chainok && (fabsf(An + (float)(n + 1)) < 3e-5f * (float)(n + 1));
  }
  v2f dw2[4];
  #pragma unroll
  for (int r = 0; r < 4; ++r) {
    dw2[r][0] = dt_w[(size_t)kd * 8 + 2 * r];
    dw2[r][1] = dt_w[(size_t)kd * 8 + 2 * r + 1];
  }
  const float dtb = dt_b[kd], dsv = Ds[kd];
  v2f h2[8];
  #pragma unroll
  for (int n = 0; n < 8; ++n) h2[n] = (v2f){0.0f, 0.0f};
  float sdt = 0.0f;
  const int seq = b * 4 + K;
  const float* ZDs = ZdtB + (size_t)seq * LL * 24;
  const float* ZCs = ZC + (size_t)seq * LL * 16;
  const float* Xb = XT + (size_t)b * LL * 128;
  float* ysb = ysz + (size_t)seq * PIX * 128;
  float* cdb = cumdtv + (size_t)seq * PIX * 128;
  const int l0 = chunk * LC;

  if (__all(chainok ? 1 : 0)) {
    #pragma unroll 1
    for (int sub = 0; sub < NSUB; ++sub) {
      const int ls = l0 + sub * SUBS;
      // stage dt/B rows (SUBS*24=240 floats) via per-wave LDS
      {
        const v2f* srcD = (const v2f*)(ZDs + (size_t)ls * 24);
        v2f* dstD = (v2f*)stD;
        #pragma unroll
        for (int i = 0; i < 2; ++i) {
          int idx = i * 64 + lane;
          if (idx < SUBS * 12) dstD[idx] = srcD[idx];
        }
      }
      int s0c = 0;
      bool needC;
      if (K == 0)      needC = (ls < PIX);
      else if (K == 2) needC = (ls + SUBS > LL - PIX);
      else             needC = true;
      if (K == 1) s0c = (5 - (ls % 5)) % 5;
      if (K == 3) s0c = (9 - (ls % 5)) % 5;
      if (needC) {
        if (K == 0 || K == 2) {
          const v2f* srcC = (const v2f*)(ZCs + (size_t)ls * 16);
          v2f* dstC = (v2f*)stC;
          #pragma unroll
          for (int i = 0; i < 2; ++i) {
            int idx = i * 64 + lane;
            if (idx < SUBS * 8) dstC[idx] = srcC[idx];
          }
        } else {
          int j = lane >> 4, col = lane & 15;
          if (j < 2) {
            int l = ls + s0c + 5 * j;
            if (l > LL - 1) l = LL - 1;
            stC[lane] = ZCs[(size_t)l * 16 + col];
          }
        }
      }
      // LDS-stage x for SUBS steps (per-wave slab)
      #pragma unroll
      for (int s = 0; s < SUBS; ++s) {
        int z = zmapT<K>(ls + s);
        xs[s * 64 + lane] = Xb[(size_t)z * 128 + d];
      }
      int zc = 0;
      if (K == 1) zc = (ls + s0c) / 5;
      if (K == 3) zc = (20479 - ls - s0c) / 5;
      int yj = 0;
      #pragma unroll
      for (int s = 0; s < SUBS; ++s) {
        const v2f* rowD = (const v2f*)(stD + s * 24);
        v2f zd0 = rowD[0], zd1 = rowD[1], zd2 = rowD[2], zd3 = rowD[3];
        v2f da = pk_mul(dw2[0], zd0);
        PK_FMA_ACC(da, dw2[1], zd1);
        PK_FMA_ACC(da, dw2[2], zd2);
        PK_FMA_ACC(da, dw2[3], zd3);
        float dtl = dtb + da[0] + da[1];
        float edt = __expf(dtl);
        float e1 = __builtin_amdgcn_rcpf(1.0f + edt);  // exp(-softplus(dtl))
        float dt = (dtl > 20.0f) ? dtl : __logf(1.0f + edt);
        sdt += dt;
        float xsv = xs[s * 64 + lane];
        float dtx = dt * xsv;
        v2f dtx2 = {dtx, dtx};
        float e2 = e1 * e1;
        v2f E[8];
        E[0] = (v2f){e1, e2};
        v2f e2s = {e2, e2};
        E[1] = pk_mul(E[0], e2s);   // e3,e4
        E[2] = pk_mul(E[1], e2s);   // e5,e6
        E[3] = pk_mul(E[2], e2s);   // e7,e8
        float e8 = E[3][1];
        v2f e8s = {e8, e8};
        E[4] = pk_mul(E[0], e8s);
        E[5] = pk_mul(E[1], e8s);
        E[6] = pk_mul(E[2], e8s);
        E[7] = pk_mul(E[3], e8s);
        const v2f* B2 = (const v2f*)(stD + s * 24 + 8);
        #pragma unroll
        for (int i = 0; i < 8; ++i) {
          v2f m = pk_mul(dtx2, B2[i]);
          PK_DECAY(h2[i], E[i], m);
        }
        bool doY;
        int z;
        if (K == 0)      { z = ls + s;            doY = (z < PIX); }
        else if (K == 2) { z = 20479 - (ls + s);  doY = (z < PIX); }
        else             { z = zc;                doY = ((s % 5) == s0c); }
        if (doY) {
          const v2f* C2 = (const v2f*)(stC + ((K == 0 || K == 2) ? s : yj) * 16);
          v2f ya = pk_mul(h2[0], C2[0]);
          #pragma unroll
          for (int i = 1; i < 8; ++i) PK_FMA_ACC(ya, h2[i], C2[i]);
          float y = fmaf(dsv, xsv, ya[0] + ya[1]);
          size_t o = (size_t)z * 128 + d;
          ysb[o] = y;
          cdb[o] = sdt;
          ++yj;
          if (K == 1) ++zc;
          if (K == 3) --zc;
        }
      }
    }
  } else {
    // general fallback (compact, never taken for this A_logs)
    float An[NS];
    #pragma unroll
    for (int n = 0; n < NS; ++n) An[n] = -__expf(A_logs[(size_t)kd * 16 + n]);
    float hs[NS];
    #pragma unroll
    for (int n = 0; n < NS; ++n) hs[n] = 0.0f;
    #pragma unroll 1
    for (int l = l0; l < l0 + LC; ++l) {
      int z = zmapT<K>(l);
      const float* rowD = ZDs + (size_t)l * 24;
      float dtl = dtb;
      #pragma unroll
      for (int r = 0; r < RR; ++r) dtl += dt_w[(size_t)kd * 8 + r] * rowD[r];
      float edt = __expf(dtl);
      float dt = (dtl > 20.0f) ? dtl : __logf(1.0f + edt);
      sdt += dt;
      float xv = Xb[(size_t)z * 128 + d];
      float dtx = dt * xv;
      #pragma unroll
      for (int n = 0; n < NS; ++n)
        hs[n] = hs[n] * __expf(dt * An[n]) + dtx * rowD[8 + n];
      if (z < PIX) {
        const float* rowC = ZCs + (size_t)l * 16;
        float y = dsv * xv;
        #pragma unroll
        for (int n = 0; n < NS; ++n) y = fmaf(hs[n], rowC[n], y);
        size_t o = (size_t)z * 128 + d;
        ysb[o] = y;
        cdb[o] = sdt;
      }
    }
    #pragma unroll
    for (int n = 0; n < 8; ++n) h2[n] = (v2f){hs[2*n], hs[2*n+1]};
  }
  float* ho = h_out + (((size_t)seq * NCHK + chunk) * 128 + d) * 16;
  #pragma unroll
  for (int n = 0; n < 8; ++n) {
    ho[2*n] = h2[n][0];
    ho[2*n+1] = h2[n][1];
  }
  sumdts[((size_t)seq * NCHK + chunk) * 128 + d] = sdt;
}

__global__ __launch_bounds__(256, 6)
void k_scan1(const float* __restrict__ XT, const float* __restrict__ ZdtB,
             const float* __restrict__ ZC,
             const float* __restrict__ dt_w, const float* __restrict__ dt_b,
             const float* __restrict__ A_logs, const float* __restrict__ Ds,
             float* __restrict__ h_out, float* __restrict__ sumdts,
             float* __restrict__ ysz, float* __restrict__ cumdtv) {
  __shared__ __align__(16) float stD_all[4][SUBS * 24];
  __shared__ __align__(16) float stC_all[4][SUBS * 16];
  __shared__ __align__(16) float xs_all[4][SUBS * 64];
  int tid = threadIdx.x, wid = tid >> 6, lane = tid & 63;
  int bid = blockIdx.x;            // B * (K0CP + 3*256) = 1640
  int bb = bid / (K0CP + 768);
  int idx = bid - bb * (K0CP + 768);
  int k, cp;
  if (idx < K0CP)            { k = 0; cp = idx; }
  else if (idx < K0CP + 256) { k = 1; cp = idx - K0CP; }
  else if (idx < K0CP + 512) { k = 2; cp = idx - (K0CP + 256); }
  else                       { k = 3; cp = idx - (K0CP + 512); }
  int chunk = cp * 2 + (wid >> 1);
  int dh = wid & 1;
  float* stD = stD_all[wid];
  float* stC = stC_all[wid];
  float* xs  = xs_all[wid];
  switch (k) {
    case 0: scan_body<0>(bb, chunk, dh, lane, XT, ZdtB, ZC, dt_w, dt_b, A_logs, Ds, h_out, sumdts, ysz, cumdtv, stD, stC, xs); break;
    case 1: scan_body<1>(bb, chunk, dh, lane, XT, ZdtB, ZC, dt_w, dt_b, A_logs, Ds, h_out, sumdts, ysz, cumdtv, stD, stC, xs); break;
    case 2: scan_body<2>(bb, chunk, dh, lane, XT, ZdtB, ZC, dt_w, dt_b, A_logs, Ds, h_out, sumdts, ysz, cumdtv, stD, stC, xs); break;
    default: scan_body<3>(bb, chunk, dh, lane, XT, ZdtB, ZC, dt_w, dt_b, A_logs, Ds, h_out, sumdts, ysz, cumdtv, stD, stC, xs); break;
  }
}

// ---- combine level A: per-group affine fold (Ag = prod a, Bg = fold b) ----
__global__ __launch_bounds__(256)
void k_comb_a(const float* __restrict__ A_logs, const float* __restrict__ sumdts,
              const float* __restrict__ h_out, float* __restrict__ Ag,
              float* __restrict__ Bg) {
  int g = blockIdx.x * 256 + threadIdx.x;   // 8*32*128*16 = 524288
  int n = g & 15;
  int d = (g >> 4) & 127;
  int grp = (g >> 11) & 31;
  int seq = g >> 16;
  int k = seq & 3;
  float An = -__expf(A_logs[(size_t)(k * 128 + d) * 16 + n]);
  float A = 1.0f, Bv = 0.0f;
  size_t cbase = (size_t)seq * NCHK + grp * GCH;
  #pragma unroll 4
  for (int j = 0; j < GCH; ++j) {
    float a = __expf(An * sumdts[(cbase + j) * 128 + d]);
    float b = h_out[((cbase + j) * 128 + d) * 16 + n];
    A *= a;
    Bv = Bv * a + b;
  }
  size_t o = (((size_t)seq * NGRP + grp) * 128 + d) * 16 + n;
  Ag[o] = A;
  Bg[o] = Bv;
}

// ---- combine level B: prefix over 32 groups ----
__global__ __launch_bounds__(256)
void k_comb_b(const float* __restrict__ Ag, const float* __restrict__ Bg,
              float* __restrict__ Hg) {
  int g = blockIdx.x * 256 + threadIdx.x;   // 8*128*16 = 16384
  int n = g & 15;
  int d = (g >> 4) & 127;
  int seq = g >> 11;
  float H = 0.0f;
  #pragma unroll
  for (int grp = 0; grp < NGRP; ++grp) {
    size_t o = (((size_t)seq * NGRP + grp) * 128 + d) * 16 + n;
    Hg[o] = H;
    H = Ag[o] * H + Bg[o];
  }
}

// ---- combine level C: replay within group -> h_in per chunk ----
__global__ __launch_bounds__(256)
void k_comb_c(const float* __restrict__ A_logs, const float* __restrict__ sumdts,
              const float* __restrict__ h_out, const float* __restrict__ Hg,
              float* __restrict__ h_in) {
  int g = blockIdx.x * 256 + threadIdx.x;   // 524288
  int n = g & 15;
  int d = (g >> 4) & 127;
  int grp = (g >> 11) & 31;
  int seq = g >> 16;
  int k = seq & 3;
  float An = -__expf(A_logs[(size_t)(k * 128 + d) * 16 + n]);
  float h = Hg[(((size_t)seq * NGRP + grp) * 128 + d) * 16 + n];
  size_t cbase = (size_t)seq * NCHK + grp * GCH;
  #pragma unroll 4
  for (int j = 0; j < GCH; ++j) {
    size_t o = ((cbase + j) * 128 + d) * 16 + n;
    h_in[o] = h;
    float a = __expf(An * sumdts[(cbase + j) * 128 + d]);
    h = a * h + h_out[o];
  }
}

// ---------------- transpose out_proj_w ----------------
__global__ __launch_bounds__(256)
void k_wt(const float* __restrict__ Wo, float* __restrict__ WT) {
  __shared__ float tl[32][33];
  int bx = blockIdx.x & 3, by = blockIdx.x >> 2;
  int t = threadIdx.x;
  int tx = t & 31, ty = t >> 5;
  #pragma unroll
  for (int i = 0; i < 4; ++i)
    tl[ty + i * 8][tx] = Wo[(size_t)(by * 32 + ty + i * 8) * 128 + bx * 32 + tx];
  __syncthreads();
  #pragma unroll
  for (int i = 0; i < 4; ++i)
    WT[(size_t)(bx * 32 + ty + i * 8) * 128 + by * 32 + tx] = tl[tx][ty + i * 8];
}

// ------- merge 4 dirs + cross-chunk fix + LayerNorm + out_proj -------
__global__ __launch_bounds__(256)
void k_merge(const float* __restrict__ ysz, const float* __restrict__ ZC,
             const float* __restrict__ A_logs, const float* __restrict__ h_in,
             const float* __restrict__ cumdt,
             const float* __restrict__ ln_g, const float* __restrict__ ln_b,
             const float* __restrict__ WT, float* __restrict__ out) {
  __shared__ __align__(16) float ynT[128][20];
  __shared__ float red[4][8][2];
  int blk = blockIdx.x;          // 512: b = blk>>8, ptile = blk&255
  int b = blk >> 8;
  int p0 = (blk & 255) * 16;
  int tid = threadIdx.x;
  int t = tid & 127;             // channel d
  int half = tid >> 7;           // 0/1
  int w = tid >> 6;              // wave 0..3
  float g = ln_g[t], bb = ln_b[t];
  bool cok[4];
  #pragma unroll
  for (int k = 0; k < 4; ++k) {
    bool c = true;
    #pragma unroll
    for (int n = 0; n < NS; ++n) {
      float An = -__expf(A_logs[(size_t)(k * 128 + t) * 16 + n]);
      c = c && (fabsf(An + (float)(n + 1)) < 3e-5f * (float)(n + 1));
    }
    cok[k] = c;
  }
  float yv[8];
  #pragma unroll
  for (int i = 0; i < 8; ++i) {
    int p = p0 + 2 * i + half;
    float y = 0.0f;
    #pragma unroll
    for (int k = 0; k < 4; ++k) {
      size_t zi = ((size_t)(b * 4 + k) * PIX + p) * 128 + t;
      float yk = ysz[zi];
      int l;
      if (k == 0)      l = p;
      else if (k == 1) l = 5 * p;
      else if (k == 2) l = 20479 - p;
      else             l = 20479 - 5 * p;
      int chunk = l / LC;
      float cd = cumdt[zi];
      const v2f* hi2 = (const v2f*)(h_in + (((size_t)(b * 4 + k) * NCHK + chunk) * 128 + t) * 16);
      const v2f* Cr2 = (const v2f*)(ZC + ((size_t)(b * 4 + k) * LL + l) * 16);
      float fix;
      if (cok[k]) {
        float q = __expf(-cd);
        float q2 = q * q;
        v2f Q[8];
        Q[0] = (v2f){q, q2};
        v2f q2s = {q2, q2};
        Q[1] = pk_mul(Q[0], q2s);
        Q[2] = pk_mul(Q[1], q2s);
        Q[3] = pk_mul(Q[2], q2s);
        float q8 = Q[3][1];
        v2f q8s = {q8, q8};
        Q[4] = pk_mul(Q[0], q8s);
        Q[5] = pk_mul(Q[1], q8s);
        Q[6] = pk_mul(Q[2], q8s);
        Q[7] = pk_mul(Q[3], q8s);
        v2f a = pk_mul(pk_mul(hi2[0], Cr2[0]), Q[0]);
        #pragma unroll
        for (int j = 1; j < 8; ++j) {
          v2f m = pk_mul(hi2[j], Cr2[j]);
          PK_FMA_ACC(a, m, Q[j]);
        }
        fix = a[0] + a[1];
      } else {
        fix = 0.0f;
        const float* hi = (const float*)hi2;
        const float* Cr = (const float*)Cr2;
        #pragma unroll
        for (int n = 0; n < NS; ++n) {
          float An = -__expf(A_logs[(size_t)(k * 128 + t) * 16 + n]);
          fix += Cr[n] * hi[n] * __expf(An * cd);
        }
      }
      y += yk + fix;
    }
    yv[i] = y;
    float s1 = y, s2 = y * y;
    #pragma unroll
    for (int off = 32; off; off >>= 1) {
      s1 += __shfl_xor(s1, off);
      s2 += __shfl_xor(s2, off);
    }
    if ((tid & 63) == 0) { red[w][i][0] = s1; red[w][i][1] = s2; }
  }
  __syncthreads();
  #pragma unroll
  for (int i = 0; i < 8; ++i) {
    int pl = 2 * i + half;
    float S1 = red[half * 2][i][0] + red[half * 2 + 1][i][0];
    float S2 = red[half * 2][i][1] + red[half * 2 + 1][i][1];
    float mu = S1 * (1.0f / 128.0f);
    float var = S2 * (1.0f / 128.0f) - mu * mu;
    float rs = rsqrtf(var + 1e-5f);
    ynT[t][pl] = (yv[i] - mu) * rs * g + bb;
  }
  __syncthreads();
  float acc[8];
  #pragma unroll
  for (int i = 0; i < 8; ++i) acc[i] = 0.0f;
  for (int dd = 0; dd < 128; ++dd) {
    float wv = WT[(size_t)dd * 128 + t];
    const float4* yr = (const float4*)(&ynT[dd][half * 8]);
    float4 ya = yr[0], yb4 = yr[1];
    acc[0] = fmaf(ya.x,  wv, acc[0]);
    acc[1] = fmaf(ya.y,  wv, acc[1]);
    acc[2] = fmaf(ya.z,  wv, acc[2]);
    acc[3] = fmaf(ya.w,  wv, acc[3]);
    acc[4] = fmaf(yb4.x, wv, acc[4]);
    acc[5] = fmaf(yb4.y, wv, acc[5]);
    acc[6] = fmaf(yb4.z, wv, acc[6]);
    acc[7] = fmaf(yb4.w, wv, acc[7]);
  }
  float* dst = out + ((size_t)b * 128 + t) * PIX + p0 + half * 8;
  *(float4*)(dst)     = make_float4(acc[0], acc[1], acc[2], acc[3]);
  *(float4*)(dst + 4) = make_float4(acc[4], acc[5], acc[6], acc[7]);
}

extern "C" void kernel_launch(void* const* d_in, const int* in_sizes, int n_in,
                              void* d_out, int out_size, void* d_ws, size_t ws_size,
                              hipStream_t stream) {
  const float* x         = (const float*)d_in[0];
  // d_in[1] record_len unused
  const float* nam       = (const float*)d_in[2];
  const float* in_proj_w = (const float*)d_in[3];
  const float* conv_w    = (const float*)d_in[4];
  const float* conv_b    = (const float*)d_in[5];
  const float* x_proj_w  = (const float*)d_in[6];
  const float* dt_w      = (const float*)d_in[7];
  const float* dt_b      = (const float*)d_in[8];
  const float* A_logs    = (const float*)d_in[9];
  const float* Ds        = (const float*)d_in[10];
  const float* ln_g      = (const float*)d_in[11];
  const float* ln_b      = (const float*)d_in[12];
  const float* out_proj_w= (const float*)d_in[13];
  float* out = (float*)d_out;
  float* ws  = (float*)d_ws;

  // workspace layout (floats), total ~32.8M (~131 MB)
  float* warped = ws;                          // 5,242,880
  float* alpha  = warped + 5242880;            //    40,960
  float* X0     = alpha  + 40960;              // 5,242,880   (end 10,526,720)
  float* XT     = X0     + 5242880;            // 5,242,880
  float* ZdtB   = XT     + 5242880;            // 3,932,160   (end 19,701,760)
  float* ZC     = ZdtB   + 3932160;            // 2,621,440
  float* sums   = ZC     + 2621440;            //   524,288
  float* ysz    = sums   + 524288;             // 4,194,304
  float* cumdt  = ysz    + 4194304;            // 4,194,304
  float* WT     = cumdt  + 4194304;            //    16,384
  float* Ag     = WT     + 16384;              //   524,288
  float* Bg     = Ag     + 524288;             //   524,288
  float* Hg     = Bg     + 524288;             //   524,288

  // aliases: h_out (8.39M) over warped+alpha+X0 (dead after k_conv);
  //          h_in  (8.39M) over XT+ZdtB (dead after k_scan1)
  float* h_out = ws;
  float* h_in  = XT;

  k_warp   <<<20480, 256, 0, stream>>>(x, nam, warped);
  k_alpha  <<<128,   512, 0, stream>>>(warped, nam, alpha);
  k_gemm_in<<<640,   256, 0, stream>>>(warped, alpha, in_proj_w, X0);
  k_conv   <<<5120,  256, 0, stream>>>(X0, conv_w, conv_b, XT);
  k_gemmZ  <<<640,   256, 0, stream>>>(XT, x_proj_w, ZdtB, ZC);
  k_scan1  <<<B_S * (K0CP + 768), 256, 0, stream>>>(XT, ZdtB, ZC, dt_w, dt_b,
                                                    A_logs, Ds, h_out, sums, ysz, cumdt);
  k_comb_a <<<2048,  256, 0, stream>>>(A_logs, sums, h_out, Ag, Bg);
  k_comb_b <<<64,    256, 0, stream>>>(Ag, Bg, Hg);
  k_comb_c <<<2048,  256, 0, stream>>>(A_logs, sums, h_out, Hg, h_in);
  k_wt     <<<16,    256, 0, stream>>>(out_proj_w, WT);
  k_merge  <<<512,   256, 0, stream>>>(ysz, ZC, A_logs, h_in, cumdt,
                                       ln_g, ln_b, WT, out);
}